// Round 1
// baseline (2965.216 us; speedup 1.0000x reference)
//
#include <hip/hip_runtime.h>

#define NN 100000
#define NE 1600000

// ---------------------------------------------------------------------------
// h0 = (1+eps) * x          (elementwise, float4)
__global__ __launch_bounds__(256) void k_init(const float* __restrict__ x,
                                              const float* __restrict__ eps,
                                              float* __restrict__ h0) {
  int i = blockIdx.x * 256 + threadIdx.x;  // over NN*16 float4s
  float s = 1.0f + eps[0];
  float4 v = ((const float4*)x)[i];
  ((float4*)h0)[i] = make_float4(s * v.x, s * v.y, s * v.z, s * v.w);
}

// ---------------------------------------------------------------------------
// h0[dst] += x[src]  over all edges. 16 threads per edge, float4 per thread,
// HW f32 atomics (unsafeAtomicAdd -> global_atomic_add_f32).
__global__ __launch_bounds__(256) void k_scatter(const int* __restrict__ src,
                                                 const int* __restrict__ dst,
                                                 const float* __restrict__ x,
                                                 float* __restrict__ h0) {
  int t = blockIdx.x * 256 + threadIdx.x;  // over NE*16
  int e = t >> 4, q = t & 15;
  int s = src[e], d = dst[e];
  float4 v = ((const float4*)x)[s * 16 + q];
  float* p = h0 + d * 64 + q * 4;
  unsafeAtomicAdd(p + 0, v.x);
  unsafeAtomicAdd(p + 1, v.y);
  unsafeAtomicAdd(p + 2, v.z);
  unsafeAtomicAdd(p + 3, v.w);
}

// ---------------------------------------------------------------------------
// h2 = relu(relu(h0@W1+b1)@W2+b2); accumulate BN sum/sumsq (f64) into stats.
// Lane f holds columns W1[:,f], W2[:,f] in 128 VGPRs; activation-row values
// broadcast via v_readlane (no LDS in the inner loop). 4 nodes per wave-iter.
__global__ __launch_bounds__(256) void k_mlp(const float* __restrict__ h0,
                                             const float* __restrict__ W1,
                                             const float* __restrict__ b1,
                                             const float* __restrict__ W2,
                                             const float* __restrict__ b2,
                                             float* __restrict__ h2,
                                             double* __restrict__ stats) {
  const int f = threadIdx.x & 63;
  const int w = threadIdx.x >> 6;
  float wc1[64], wc2[64];
#pragma unroll
  for (int k = 0; k < 64; k++) wc1[k] = W1[k * 64 + f];
#pragma unroll
  for (int k = 0; k < 64; k++) wc2[k] = W2[k * 64 + f];
  const float bb1 = b1[f], bb2 = b2[f];
  double psum = 0.0, psq = 0.0;
  const int groups = NN / 4;  // 25000 exact, no tail
  for (int g = blockIdx.x * 4 + w; g < groups; g += gridDim.x * 4) {
    const int n0 = g * 4;
    float r[4], a[4];
#pragma unroll
    for (int j = 0; j < 4; j++) r[j] = h0[(n0 + j) * 64 + f];
#pragma unroll
    for (int j = 0; j < 4; j++) a[j] = bb1;
#pragma unroll
    for (int k = 0; k < 64; k++) {
#pragma unroll
      for (int j = 0; j < 4; j++) {
        float s = __int_as_float(__builtin_amdgcn_readlane(__float_as_int(r[j]), k));
        a[j] = fmaf(s, wc1[k], a[j]);
      }
    }
#pragma unroll
    for (int j = 0; j < 4; j++) r[j] = fmaxf(a[j], 0.0f);
#pragma unroll
    for (int j = 0; j < 4; j++) a[j] = bb2;
#pragma unroll
    for (int k = 0; k < 64; k++) {
#pragma unroll
      for (int j = 0; j < 4; j++) {
        float s = __int_as_float(__builtin_amdgcn_readlane(__float_as_int(r[j]), k));
        a[j] = fmaf(s, wc2[k], a[j]);
      }
    }
#pragma unroll
    for (int j = 0; j < 4; j++) {
      float v = fmaxf(a[j], 0.0f);
      h2[(n0 + j) * 64 + f] = v;
      psum += (double)v;
      psq += (double)v * (double)v;
    }
  }
  __shared__ double ls[4][64], lq[4][64];
  ls[w][f] = psum;
  lq[w][f] = psq;
  __syncthreads();
  if (w == 0) {
    double s = ls[0][f] + ls[1][f] + ls[2][f] + ls[3][f];
    double q = lq[0][f] + lq[1][f] + lq[2][f] + lq[3][f];
    unsafeAtomicAdd(&stats[f], s);
    unsafeAtomicAdd(&stats[64 + f], q);
  }
}

// ---------------------------------------------------------------------------
// stats -> per-feature affine A (scale), B (shift): out = h*A + B
__global__ void k_bnfin(const double* __restrict__ stats, const float* __restrict__ gam,
                        const float* __restrict__ bet, float* __restrict__ AB) {
  int f = threadIdx.x;  // 64 threads
  double mean = stats[f] * (1.0 / NN);
  double var = stats[64 + f] * (1.0 / NN) - mean * mean;
  if (var < 0.0) var = 0.0;
  float rstd = (float)(1.0 / sqrt(var + 1e-5));
  float A = gam[f] * rstd;
  float B = bet[f] - (float)mean * A;
  AB[f] = A;
  AB[64 + f] = B;
}

// ---------------------------------------------------------------------------
// x2 = BN1(h2); h0b = (1+eps2)*x2   (fused elementwise, float4)
__global__ __launch_bounds__(256) void k_apply_init(const float* __restrict__ h2,
                                                    const float* __restrict__ AB,
                                                    const float* __restrict__ eps,
                                                    float* __restrict__ x2,
                                                    float* __restrict__ h0b) {
  int i = blockIdx.x * 256 + threadIdx.x;  // over NN*16
  int q = i & 15;
  float4 v = ((const float4*)h2)[i];
  float4 A = ((const float4*)AB)[q];
  float4 B = ((const float4*)(AB + 64))[q];
  float s = 1.0f + eps[0];
  float4 xo = make_float4(fmaf(v.x, A.x, B.x), fmaf(v.y, A.y, B.y),
                          fmaf(v.z, A.z, B.z), fmaf(v.w, A.w, B.w));
  ((float4*)x2)[i] = xo;
  ((float4*)h0b)[i] = make_float4(s * xo.x, s * xo.y, s * xo.z, s * xo.w);
}

// ---------------------------------------------------------------------------
// h = BN2(h2); out[0:N*64] = h; out[N*64:] = log_softmax(h) per row.
__global__ __launch_bounds__(256) void k_out(const float* __restrict__ h2,
                                             const float* __restrict__ AB,
                                             float* __restrict__ out) {
  int f = threadIdx.x & 63;
  int n = blockIdx.x * 4 + (threadIdx.x >> 6);  // 25000 blocks * 4 = NN exact
  float v = h2[n * 64 + f];
  float h = fmaf(v, AB[f], AB[64 + f]);
  float m = h;
#pragma unroll
  for (int off = 32; off; off >>= 1) m = fmaxf(m, __shfl_xor(m, off, 64));
  float e = expf(h - m);
  float ssum = e;
#pragma unroll
  for (int off = 32; off; off >>= 1) ssum += __shfl_xor(ssum, off, 64);
  float lsm = (h - m) - logf(ssum);
  out[n * 64 + f] = h;
  out[(size_t)NN * 64 + n * 64 + f] = lsm;
}

// ---------------------------------------------------------------------------
extern "C" void kernel_launch(void* const* d_in, const int* in_sizes, int n_in,
                              void* d_out, int out_size, void* d_ws, size_t ws_size,
                              hipStream_t stream) {
  const float* x = (const float*)d_in[0];
  const int* ei = (const int*)d_in[1];  // [2, E] int32 per harness convention
  const float* W1 = (const float*)d_in[2];
  const float* b1 = (const float*)d_in[3];
  const float* W2 = (const float*)d_in[4];
  const float* b2 = (const float*)d_in[5];
  const float* g1 = (const float*)d_in[6];
  const float* bt1 = (const float*)d_in[7];
  const float* e1 = (const float*)d_in[8];
  const float* W3 = (const float*)d_in[9];
  const float* b3 = (const float*)d_in[10];
  const float* W4 = (const float*)d_in[11];
  const float* b4 = (const float*)d_in[12];
  const float* g2 = (const float*)d_in[13];
  const float* bt2 = (const float*)d_in[14];
  const float* e2 = (const float*)d_in[15];
  const int* src = ei;
  const int* dst = ei + NE;

  char* ws = (char*)d_ws;
  float* h0 = (float*)(ws);                  // 25.6 MB  (agg buf, both layers)
  float* hm = (float*)(ws + 25600000);       // 25.6 MB  (h2a, then h2b)
  float* x2 = (float*)(ws + 51200000);       // 25.6 MB  (BN1 output)
  double* st1 = (double*)(ws + 76800000);    // 128 f64
  double* st2 = (double*)(ws + 76801024);    // 128 f64
  float* AB1 = (float*)(ws + 76802048);      // 128 f32
  float* AB2 = (float*)(ws + 76802560);      // 128 f32
  float* out = (float*)d_out;

  hipMemsetAsync(ws + 76800000, 0, 2048, stream);  // zero BN stat accumulators

  // Layer 1
  k_init<<<NN * 16 / 256, 256, 0, stream>>>(x, e1, h0);
  k_scatter<<<NE * 16 / 256, 256, 0, stream>>>(src, dst, x, h0);
  k_mlp<<<1024, 256, 0, stream>>>(h0, W1, b1, W2, b2, hm, st1);
  k_bnfin<<<1, 64, 0, stream>>>(st1, g1, bt1, AB1);
  // Layer 2 (h0 buffer reused as agg buf, hm reused for h2b)
  k_apply_init<<<NN * 16 / 256, 256, 0, stream>>>(hm, AB1, e2, x2, h0);
  k_scatter<<<NE * 16 / 256, 256, 0, stream>>>(src, dst, x2, h0);
  k_mlp<<<1024, 256, 0, stream>>>(h0, W3, b3, W4, b4, hm, st2);
  k_bnfin<<<1, 64, 0, stream>>>(st2, g2, bt2, AB2);
  // Epilogue: BN2 + log_softmax -> d_out
  k_out<<<NN / 4, 256, 0, stream>>>(hm, AB2, out);
}

// Round 3
// 700.418 us; speedup vs baseline: 4.2335x; 4.2335x over previous
//
#include <hip/hip_runtime.h>

#define NN 100000
#define NE 1600000

// ---------------------------------------------------------------------------
// CSR build step 1: histogram of incoming-edge counts per destination node.
__global__ __launch_bounds__(256) void k_hist(const int* __restrict__ dst,
                                              int* __restrict__ deg) {
  int e = blockIdx.x * 256 + threadIdx.x;  // NE exact (6250*256)
  atomicAdd(&deg[dst[e]], 1);
}

// CSR build step 2: per-block sums of deg (391 blocks over 100000).
__global__ __launch_bounds__(256) void k_bsum(const int* __restrict__ deg,
                                              int* __restrict__ bsum) {
  __shared__ int sh[256];
  int i = blockIdx.x * 256 + threadIdx.x;
  sh[threadIdx.x] = (i < NN) ? deg[i] : 0;
  __syncthreads();
  for (int off = 128; off; off >>= 1) {
    if (threadIdx.x < off) sh[threadIdx.x] += sh[threadIdx.x + off];
    __syncthreads();
  }
  if (threadIdx.x == 0) bsum[blockIdx.x] = sh[0];
}

// CSR build step 3: serial exclusive scan of 391 block sums (1 thread, ~µs).
__global__ void k_scanB(int* __restrict__ bsum, int* __restrict__ rowptr) {
  if (threadIdx.x == 0) {
    int run = 0;
    for (int b = 0; b < 391; b++) { int t = bsum[b]; bsum[b] = run; run += t; }
    rowptr[NN] = NE;
  }
}

// CSR build step 4: rowptr[i] = bsum[block] + exclusive-scan-within-block.
__global__ __launch_bounds__(256) void k_scan3(const int* __restrict__ deg,
                                               const int* __restrict__ bsum,
                                               int* __restrict__ rowptr) {
  __shared__ int sh[256];
  int i = blockIdx.x * 256 + threadIdx.x;
  int v = (i < NN) ? deg[i] : 0;
  sh[threadIdx.x] = v;
  __syncthreads();
  for (int off = 1; off < 256; off <<= 1) {
    int t = (threadIdx.x >= off) ? sh[threadIdx.x - off] : 0;
    __syncthreads();
    sh[threadIdx.x] += t;
    __syncthreads();
  }
  if (i < NN) rowptr[i] = bsum[blockIdx.x] + sh[threadIdx.x] - v;
}

// CSR build step 5: place src of each edge into its dst's row segment.
__global__ __launch_bounds__(256) void k_fill(const int* __restrict__ src,
                                              const int* __restrict__ dst,
                                              const int* __restrict__ rowptr,
                                              int* __restrict__ cursor,
                                              int* __restrict__ csr) {
  int e = blockIdx.x * 256 + threadIdx.x;  // NE exact
  int d = dst[e];
  int p = atomicAdd(&cursor[d], 1);
  csr[rowptr[d] + p] = src[e];
}

// ---------------------------------------------------------------------------
// agg[n] = (1+eps) * pre(x[n]) + sum_{s in N(n)} pre(x[s]),
// pre = identity (layer 1) or BN1 affine (layer 2, fused). 64 lanes per node.
template <bool BN>
__global__ __launch_bounds__(256) void k_gather(const float* __restrict__ xin,
                                                const int* __restrict__ rowptr,
                                                const int* __restrict__ csr,
                                                const float* __restrict__ eps,
                                                const float* __restrict__ AB,
                                                float* __restrict__ agg) {
  int f = threadIdx.x & 63;
  int n = blockIdx.x * 4 + (threadIdx.x >> 6);  // 25000*4 = NN exact
  float A = 1.0f, Bv = 0.0f;
  if (BN) { A = AB[f]; Bv = AB[64 + f]; }
  float self = xin[n * 64 + f];
  if (BN) self = fmaf(self, A, Bv);
  float acc = (1.0f + eps[0]) * self;
  int beg = rowptr[n], end = rowptr[n + 1];
  for (int j = beg; j < end; j++) {
    int s = csr[j];  // same addr across the 64-lane group -> broadcast
    float v = xin[s * 64 + f];
    acc += BN ? fmaf(v, A, Bv) : v;
  }
  agg[n * 64 + f] = acc;
}

// ---------------------------------------------------------------------------
// h2 = relu(relu(h0@W1+b1)@W2+b2); accumulate BN sum/sumsq (f64) into stats.
__global__ __launch_bounds__(256) void k_mlp(const float* __restrict__ h0,
                                             const float* __restrict__ W1,
                                             const float* __restrict__ b1,
                                             const float* __restrict__ W2,
                                             const float* __restrict__ b2,
                                             float* __restrict__ h2,
                                             double* __restrict__ stats) {
  const int f = threadIdx.x & 63;
  const int w = threadIdx.x >> 6;
  float wc1[64], wc2[64];
#pragma unroll
  for (int k = 0; k < 64; k++) wc1[k] = W1[k * 64 + f];
#pragma unroll
  for (int k = 0; k < 64; k++) wc2[k] = W2[k * 64 + f];
  const float bb1 = b1[f], bb2 = b2[f];
  double psum = 0.0, psq = 0.0;
  const int groups = NN / 4;  // 25000 exact
  for (int g = blockIdx.x * 4 + w; g < groups; g += gridDim.x * 4) {
    const int n0 = g * 4;
    float r[4], a[4];
#pragma unroll
    for (int j = 0; j < 4; j++) r[j] = h0[(n0 + j) * 64 + f];
#pragma unroll
    for (int j = 0; j < 4; j++) a[j] = bb1;
#pragma unroll
    for (int k = 0; k < 64; k++) {
#pragma unroll
      for (int j = 0; j < 4; j++) {
        float s = __int_as_float(__builtin_amdgcn_readlane(__float_as_int(r[j]), k));
        a[j] = fmaf(s, wc1[k], a[j]);
      }
    }
#pragma unroll
    for (int j = 0; j < 4; j++) r[j] = fmaxf(a[j], 0.0f);
#pragma unroll
    for (int j = 0; j < 4; j++) a[j] = bb2;
#pragma unroll
    for (int k = 0; k < 64; k++) {
#pragma unroll
      for (int j = 0; j < 4; j++) {
        float s = __int_as_float(__builtin_amdgcn_readlane(__float_as_int(r[j]), k));
        a[j] = fmaf(s, wc2[k], a[j]);
      }
    }
#pragma unroll
    for (int j = 0; j < 4; j++) {
      float v = fmaxf(a[j], 0.0f);
      h2[(n0 + j) * 64 + f] = v;
      psum += (double)v;
      psq += (double)v * (double)v;
    }
  }
  __shared__ double ls[4][64], lq[4][64];
  ls[w][f] = psum;
  lq[w][f] = psq;
  __syncthreads();
  if (w == 0) {
    double s = ls[0][f] + ls[1][f] + ls[2][f] + ls[3][f];
    double q = lq[0][f] + lq[1][f] + lq[2][f] + lq[3][f];
    unsafeAtomicAdd(&stats[f], s);
    unsafeAtomicAdd(&stats[64 + f], q);
  }
}

// ---------------------------------------------------------------------------
// stats -> per-feature affine A (scale), B (shift): out = h*A + B
__global__ void k_bnfin(const double* __restrict__ stats, const float* __restrict__ gam,
                        const float* __restrict__ bet, float* __restrict__ AB) {
  int f = threadIdx.x;  // 64 threads
  double mean = stats[f] * (1.0 / NN);
  double var = stats[64 + f] * (1.0 / NN) - mean * mean;
  if (var < 0.0) var = 0.0;
  float rstd = (float)(1.0 / sqrt(var + 1e-5));
  float A = gam[f] * rstd;
  float B = bet[f] - (float)mean * A;
  AB[f] = A;
  AB[64 + f] = B;
}

// ---------------------------------------------------------------------------
// h = BN2(h2); out[0:N*64] = h; out[N*64:] = log_softmax(h) per row.
__global__ __launch_bounds__(256) void k_out(const float* __restrict__ h2,
                                             const float* __restrict__ AB,
                                             float* __restrict__ out) {
  int f = threadIdx.x & 63;
  int n = blockIdx.x * 4 + (threadIdx.x >> 6);  // 25000*4 = NN exact
  float v = h2[n * 64 + f];
  float h = fmaf(v, AB[f], AB[64 + f]);
  float m = h;
#pragma unroll
  for (int off = 32; off; off >>= 1) m = fmaxf(m, __shfl_xor(m, off, 64));
  float e = expf(h - m);
  float ssum = e;
#pragma unroll
  for (int off = 32; off; off >>= 1) ssum += __shfl_xor(ssum, off, 64);
  float lsm = (h - m) - logf(ssum);
  out[n * 64 + f] = h;
  out[(size_t)NN * 64 + n * 64 + f] = lsm;
}

// ---------------------------------------------------------------------------
extern "C" void kernel_launch(void* const* d_in, const int* in_sizes, int n_in,
                              void* d_out, int out_size, void* d_ws, size_t ws_size,
                              hipStream_t stream) {
  const float* x = (const float*)d_in[0];
  const int* ei = (const int*)d_in[1];  // [2, E] as int32
  const float* W1 = (const float*)d_in[2];
  const float* b1 = (const float*)d_in[3];
  const float* W2 = (const float*)d_in[4];
  const float* b2 = (const float*)d_in[5];
  const float* g1 = (const float*)d_in[6];
  const float* bt1 = (const float*)d_in[7];
  const float* e1 = (const float*)d_in[8];
  const float* W3 = (const float*)d_in[9];
  const float* b3 = (const float*)d_in[10];
  const float* W4 = (const float*)d_in[11];
  const float* b4 = (const float*)d_in[12];
  const float* g2 = (const float*)d_in[13];
  const float* bt2 = (const float*)d_in[14];
  const float* e2 = (const float*)d_in[15];
  const int* src = ei;
  const int* dst = ei + NE;

  char* ws = (char*)d_ws;
  float* bufA = (float*)(ws);                   // 25.6 MB ping
  float* bufB = (float*)(ws + 25600000);        // 25.6 MB pong
  int* rowptr = (int*)(ws + 51200000);          // 100001 ints (400004 B)
  int* tmp = (int*)(ws + 51601408);             // 100000 ints (deg, then cursor)
  int* csr = (int*)(ws + 52002816);             // 1.6M ints (6.4 MB)
  int* bsum = (int*)(ws + 58402816);            // 512 ints (2048 B)
  double* st1 = (double*)(ws + 58404864);       // 128 f64 = 1024 B
  double* st2 = (double*)(ws + 58405888);       // 128 f64 = 1024 B  (NO overlap)
  float* AB1 = (float*)(ws + 58406912);         // 128 f32 = 512 B
  float* AB2 = (float*)(ws + 58407424);         // 128 f32 = 512 B
  float* out = (float*)d_out;

  hipMemsetAsync(ws + 58404864, 0, 2048, stream);  // zero st1 + st2 fully

  // --- CSR build (once; shared by both layers) ---
  hipMemsetAsync(tmp, 0, 400000, stream);
  k_hist<<<NE / 256, 256, 0, stream>>>(dst, tmp);
  k_bsum<<<391, 256, 0, stream>>>(tmp, bsum);
  k_scanB<<<1, 64, 0, stream>>>(bsum, rowptr);
  k_scan3<<<391, 256, 0, stream>>>(tmp, bsum, rowptr);
  hipMemsetAsync(tmp, 0, 400000, stream);
  k_fill<<<NE / 256, 256, 0, stream>>>(src, dst, rowptr, tmp, csr);

  // --- Layer 1 ---
  k_gather<false><<<NN / 4, 256, 0, stream>>>(x, rowptr, csr, e1, nullptr, bufA);
  k_mlp<<<1024, 256, 0, stream>>>(bufA, W1, b1, W2, b2, bufB, st1);
  k_bnfin<<<1, 64, 0, stream>>>(st1, g1, bt1, AB1);
  // --- Layer 2 (BN1-apply fused into the gather) ---
  k_gather<true><<<NN / 4, 256, 0, stream>>>(bufB, rowptr, csr, e2, AB1, bufA);
  k_mlp<<<1024, 256, 0, stream>>>(bufA, W3, b3, W4, b4, bufB, st2);
  k_bnfin<<<1, 64, 0, stream>>>(st2, g2, bt2, AB2);
  // --- Epilogue: BN2 + log_softmax ---
  k_out<<<NN / 4, 256, 0, stream>>>(bufB, AB2, out);
}

// Round 4
// 568.011 us; speedup vs baseline: 5.2204x; 1.2331x over previous
//
#include <hip/hip_runtime.h>

#define NN 100000
#define NE 1600000

// ---------------------------------------------------------------------------
// CSR build step 1: histogram of incoming-edge counts per destination node.
__global__ __launch_bounds__(256) void k_hist(const int* __restrict__ dst,
                                              int* __restrict__ deg) {
  int e = blockIdx.x * 256 + threadIdx.x;  // NE exact (6250*256)
  atomicAdd(&deg[dst[e]], 1);
}

// CSR build step 2: per-block sums of deg (391 blocks over 100000).
__global__ __launch_bounds__(256) void k_bsum(const int* __restrict__ deg,
                                              int* __restrict__ bsum) {
  __shared__ int sh[256];
  int i = blockIdx.x * 256 + threadIdx.x;
  sh[threadIdx.x] = (i < NN) ? deg[i] : 0;
  __syncthreads();
  for (int off = 128; off; off >>= 1) {
    if (threadIdx.x < off) sh[threadIdx.x] += sh[threadIdx.x + off];
    __syncthreads();
  }
  if (threadIdx.x == 0) bsum[blockIdx.x] = sh[0];
}

// CSR build step 3: PARALLEL exclusive scan of 391 block sums (1 block).
__global__ __launch_bounds__(512) void k_scanB(int* __restrict__ bsum,
                                               int* __restrict__ rowptr) {
  __shared__ int sh[512];
  int t = threadIdx.x;
  int v = (t < 391) ? bsum[t] : 0;
  sh[t] = v;
  __syncthreads();
  for (int off = 1; off < 512; off <<= 1) {
    int u = (t >= off) ? sh[t - off] : 0;
    __syncthreads();
    sh[t] += u;
    __syncthreads();
  }
  if (t < 391) bsum[t] = sh[t] - v;  // exclusive
  if (t == 0) rowptr[NN] = NE;
}

// CSR build step 4: rowptr[i] = bsum[block] + exclusive-scan-within-block.
__global__ __launch_bounds__(256) void k_scan3(const int* __restrict__ deg,
                                               const int* __restrict__ bsum,
                                               int* __restrict__ rowptr) {
  __shared__ int sh[256];
  int i = blockIdx.x * 256 + threadIdx.x;
  int v = (i < NN) ? deg[i] : 0;
  sh[threadIdx.x] = v;
  __syncthreads();
  for (int off = 1; off < 256; off <<= 1) {
    int t = (threadIdx.x >= off) ? sh[threadIdx.x - off] : 0;
    __syncthreads();
    sh[threadIdx.x] += t;
    __syncthreads();
  }
  if (i < NN) rowptr[i] = bsum[blockIdx.x] + sh[threadIdx.x] - v;
}

// CSR build step 5: place src of each edge into its dst's row segment.
__global__ __launch_bounds__(256) void k_fill(const int* __restrict__ src,
                                              const int* __restrict__ dst,
                                              const int* __restrict__ rowptr,
                                              int* __restrict__ cursor,
                                              int* __restrict__ csr) {
  int e = blockIdx.x * 256 + threadIdx.x;  // NE exact
  int d = dst[e];
  int p = atomicAdd(&cursor[d], 1);
  csr[rowptr[d] + p] = src[e];
}

// ---------------------------------------------------------------------------
// agg[n] = (1+eps) * pre(x[n]) + sum_{s in N(n)} pre(x[s]),
// pre = identity (layer 1) or BN1 affine (layer 2, fused). One wave per node
// group of 64 feats; neighbor loop unrolled 4-wide with int4 index loads and
// 4 independent accumulators -> 4 outstanding row loads per wave.
template <bool BN>
__global__ __launch_bounds__(256) void k_gather(const float* __restrict__ xin,
                                                const int* __restrict__ rowptr,
                                                const int* __restrict__ csr,
                                                const float* __restrict__ eps,
                                                const float* __restrict__ AB,
                                                float* __restrict__ agg) {
  int f = threadIdx.x & 63;
  int n = blockIdx.x * 4 + (threadIdx.x >> 6);  // 25000*4 = NN exact
  float A = 1.0f, Bv = 0.0f;
  if (BN) { A = AB[f]; Bv = AB[64 + f]; }
  float self = xin[n * 64 + f];
  if (BN) self = fmaf(self, A, Bv);
  float a0 = (1.0f + eps[0]) * self, a1 = 0.0f, a2 = 0.0f, a3 = 0.0f;
  int j = rowptr[n], end = rowptr[n + 1];
  // prologue: align j to 4 for int4 index loads
  while (j < end && (j & 3)) {
    int s = csr[j++];
    float v = xin[s * 64 + f];
    a0 += BN ? fmaf(v, A, Bv) : v;
  }
  const int4* c4 = (const int4*)csr;
  for (; j + 4 <= end; j += 4) {
    int4 s4 = c4[j >> 2];
    float v0 = xin[s4.x * 64 + f];
    float v1 = xin[s4.y * 64 + f];
    float v2 = xin[s4.z * 64 + f];
    float v3 = xin[s4.w * 64 + f];
    a0 += BN ? fmaf(v0, A, Bv) : v0;
    a1 += BN ? fmaf(v1, A, Bv) : v1;
    a2 += BN ? fmaf(v2, A, Bv) : v2;
    a3 += BN ? fmaf(v3, A, Bv) : v3;
  }
  for (; j < end; j++) {
    int s = csr[j];
    float v = xin[s * 64 + f];
    a0 += BN ? fmaf(v, A, Bv) : v;
  }
  agg[n * 64 + f] = (a0 + a1) + (a2 + a3);
}

// ---------------------------------------------------------------------------
// h2 = relu(relu(h0@W1+b1)@W2+b2); accumulate BN sum/sumsq (f64) into stats.
__global__ __launch_bounds__(256) void k_mlp(const float* __restrict__ h0,
                                             const float* __restrict__ W1,
                                             const float* __restrict__ b1,
                                             const float* __restrict__ W2,
                                             const float* __restrict__ b2,
                                             float* __restrict__ h2,
                                             double* __restrict__ stats) {
  const int f = threadIdx.x & 63;
  const int w = threadIdx.x >> 6;
  float wc1[64], wc2[64];
#pragma unroll
  for (int k = 0; k < 64; k++) wc1[k] = W1[k * 64 + f];
#pragma unroll
  for (int k = 0; k < 64; k++) wc2[k] = W2[k * 64 + f];
  const float bb1 = b1[f], bb2 = b2[f];
  double psum = 0.0, psq = 0.0;
  const int groups = NN / 4;  // 25000 exact
  for (int g = blockIdx.x * 4 + w; g < groups; g += gridDim.x * 4) {
    const int n0 = g * 4;
    float r[4], a[4];
#pragma unroll
    for (int j = 0; j < 4; j++) r[j] = h0[(n0 + j) * 64 + f];
#pragma unroll
    for (int j = 0; j < 4; j++) a[j] = bb1;
#pragma unroll
    for (int k = 0; k < 64; k++) {
#pragma unroll
      for (int j = 0; j < 4; j++) {
        float s = __int_as_float(__builtin_amdgcn_readlane(__float_as_int(r[j]), k));
        a[j] = fmaf(s, wc1[k], a[j]);
      }
    }
#pragma unroll
    for (int j = 0; j < 4; j++) r[j] = fmaxf(a[j], 0.0f);
#pragma unroll
    for (int j = 0; j < 4; j++) a[j] = bb2;
#pragma unroll
    for (int k = 0; k < 64; k++) {
#pragma unroll
      for (int j = 0; j < 4; j++) {
        float s = __int_as_float(__builtin_amdgcn_readlane(__float_as_int(r[j]), k));
        a[j] = fmaf(s, wc2[k], a[j]);
      }
    }
#pragma unroll
    for (int j = 0; j < 4; j++) {
      float v = fmaxf(a[j], 0.0f);
      h2[(n0 + j) * 64 + f] = v;
      psum += (double)v;
      psq += (double)v * (double)v;
    }
  }
  __shared__ double ls[4][64], lq[4][64];
  ls[w][f] = psum;
  lq[w][f] = psq;
  __syncthreads();
  if (w == 0) {
    double s = ls[0][f] + ls[1][f] + ls[2][f] + ls[3][f];
    double q = lq[0][f] + lq[1][f] + lq[2][f] + lq[3][f];
    unsafeAtomicAdd(&stats[f], s);
    unsafeAtomicAdd(&stats[64 + f], q);
  }
}

// ---------------------------------------------------------------------------
// stats -> per-feature affine A (scale), B (shift): out = h*A + B
__global__ void k_bnfin(const double* __restrict__ stats, const float* __restrict__ gam,
                        const float* __restrict__ bet, float* __restrict__ AB) {
  int f = threadIdx.x;  // 64 threads
  double mean = stats[f] * (1.0 / NN);
  double var = stats[64 + f] * (1.0 / NN) - mean * mean;
  if (var < 0.0) var = 0.0;
  float rstd = (float)(1.0 / sqrt(var + 1e-5));
  float A = gam[f] * rstd;
  float B = bet[f] - (float)mean * A;
  AB[f] = A;
  AB[64 + f] = B;
}

// ---------------------------------------------------------------------------
// h = BN2(h2); out[0:N*64] = h; out[N*64:] = log_softmax(h) per row.
__global__ __launch_bounds__(256) void k_out(const float* __restrict__ h2,
                                             const float* __restrict__ AB,
                                             float* __restrict__ out) {
  int f = threadIdx.x & 63;
  int n = blockIdx.x * 4 + (threadIdx.x >> 6);  // 25000*4 = NN exact
  float v = h2[n * 64 + f];
  float h = fmaf(v, AB[f], AB[64 + f]);
  float m = h;
#pragma unroll
  for (int off = 32; off; off >>= 1) m = fmaxf(m, __shfl_xor(m, off, 64));
  float e = expf(h - m);
  float ssum = e;
#pragma unroll
  for (int off = 32; off; off >>= 1) ssum += __shfl_xor(ssum, off, 64);
  float lsm = (h - m) - logf(ssum);
  out[n * 64 + f] = h;
  out[(size_t)NN * 64 + n * 64 + f] = lsm;
}

// ---------------------------------------------------------------------------
extern "C" void kernel_launch(void* const* d_in, const int* in_sizes, int n_in,
                              void* d_out, int out_size, void* d_ws, size_t ws_size,
                              hipStream_t stream) {
  const float* x = (const float*)d_in[0];
  const int* ei = (const int*)d_in[1];  // [2, E] as int32
  const float* W1 = (const float*)d_in[2];
  const float* b1 = (const float*)d_in[3];
  const float* W2 = (const float*)d_in[4];
  const float* b2 = (const float*)d_in[5];
  const float* g1 = (const float*)d_in[6];
  const float* bt1 = (const float*)d_in[7];
  const float* e1 = (const float*)d_in[8];
  const float* W3 = (const float*)d_in[9];
  const float* b3 = (const float*)d_in[10];
  const float* W4 = (const float*)d_in[11];
  const float* b4 = (const float*)d_in[12];
  const float* g2 = (const float*)d_in[13];
  const float* bt2 = (const float*)d_in[14];
  const float* e2 = (const float*)d_in[15];
  const int* src = ei;
  const int* dst = ei + NE;

  char* ws = (char*)d_ws;
  float* bufA = (float*)(ws);                   // 25.6 MB ping
  float* bufB = (float*)(ws + 25600000);        // 25.6 MB pong
  int* rowptr = (int*)(ws + 51200000);          // 100001 ints (400004 B)
  int* tmp = (int*)(ws + 51601408);             // 100000 ints (deg, then cursor)
  int* csr = (int*)(ws + 52002816);             // 1.6M ints (6.4 MB), 16B-aligned
  int* bsum = (int*)(ws + 58402816);            // 512 ints (2048 B)
  double* st1 = (double*)(ws + 58404864);       // 128 f64 = 1024 B
  double* st2 = (double*)(ws + 58405888);       // 128 f64 = 1024 B
  float* AB1 = (float*)(ws + 58406912);         // 128 f32 = 512 B
  float* AB2 = (float*)(ws + 58407424);         // 128 f32 = 512 B
  float* out = (float*)d_out;

  hipMemsetAsync(ws + 58404864, 0, 2048, stream);  // zero st1 + st2

  // --- CSR build (once; shared by both layers) ---
  hipMemsetAsync(tmp, 0, 400000, stream);
  k_hist<<<NE / 256, 256, 0, stream>>>(dst, tmp);
  k_bsum<<<391, 256, 0, stream>>>(tmp, bsum);
  k_scanB<<<1, 512, 0, stream>>>(bsum, rowptr);
  k_scan3<<<391, 256, 0, stream>>>(tmp, bsum, rowptr);
  hipMemsetAsync(tmp, 0, 400000, stream);
  k_fill<<<NE / 256, 256, 0, stream>>>(src, dst, rowptr, tmp, csr);

  // --- Layer 1 ---
  k_gather<false><<<NN / 4, 256, 0, stream>>>(x, rowptr, csr, e1, nullptr, bufA);
  k_mlp<<<1024, 256, 0, stream>>>(bufA, W1, b1, W2, b2, bufB, st1);
  k_bnfin<<<1, 64, 0, stream>>>(st1, g1, bt1, AB1);
  // --- Layer 2 (BN1-apply fused into the gather) ---
  k_gather<true><<<NN / 4, 256, 0, stream>>>(bufB, rowptr, csr, e2, AB1, bufA);
  k_mlp<<<1024, 256, 0, stream>>>(bufA, W3, b3, W4, b4, bufB, st2);
  k_bnfin<<<1, 64, 0, stream>>>(st2, g2, bt2, AB2);
  // --- Epilogue: BN2 + log_softmax ---
  k_out<<<NN / 4, 256, 0, stream>>>(bufB, AB2, out);
}

// Round 5
// 510.528 us; speedup vs baseline: 5.8081x; 1.1126x over previous
//
#include <hip/hip_runtime.h>

#define NN 100000
#define NE 1600000

typedef __attribute__((ext_vector_type(8))) short short8;
typedef __attribute__((ext_vector_type(4))) float floatx4;

__device__ __forceinline__ unsigned short f2bf(float f) {
  unsigned u = __float_as_uint(f);
  u += 0x7fffu + ((u >> 16) & 1u);  // RNE
  return (unsigned short)(u >> 16);
}
__device__ __forceinline__ float bf2f(unsigned short b) {
  return __uint_as_float(((unsigned)b) << 16);
}

// ---------------------------------------------------------------------------
// Convert the 4 weight matrices (each 64x64 f32 row-major) to bf16.
__global__ __launch_bounds__(256) void k_cvtW(const float* __restrict__ W1,
                                              const float* __restrict__ W2,
                                              const float* __restrict__ W3,
                                              const float* __restrict__ W4,
                                              unsigned short* __restrict__ Wb) {
  int i = blockIdx.x * 256 + threadIdx.x;  // 16 blocks * 256 = 4096 exact
  Wb[i] = f2bf(W1[i]);
  Wb[4096 + i] = f2bf(W2[i]);
  Wb[8192 + i] = f2bf(W3[i]);
  Wb[12288 + i] = f2bf(W4[i]);
}

// ---------------------------------------------------------------------------
// CSR build step 1: histogram of incoming-edge counts per destination node.
__global__ __launch_bounds__(256) void k_hist(const int* __restrict__ dst,
                                              int* __restrict__ deg) {
  int e = blockIdx.x * 256 + threadIdx.x;  // NE exact
  atomicAdd(&deg[dst[e]], 1);
}

// CSR build step 2: per-block sums of deg (391 blocks over 100000).
__global__ __launch_bounds__(256) void k_bsum(const int* __restrict__ deg,
                                              int* __restrict__ bsum) {
  __shared__ int sh[256];
  int i = blockIdx.x * 256 + threadIdx.x;
  sh[threadIdx.x] = (i < NN) ? deg[i] : 0;
  __syncthreads();
  for (int off = 128; off; off >>= 1) {
    if (threadIdx.x < off) sh[threadIdx.x] += sh[threadIdx.x + off];
    __syncthreads();
  }
  if (threadIdx.x == 0) bsum[blockIdx.x] = sh[0];
}

// CSR build step 3: parallel exclusive scan of 391 block sums (1 block).
__global__ __launch_bounds__(512) void k_scanB(int* __restrict__ bsum,
                                               int* __restrict__ rowptr) {
  __shared__ int sh[512];
  int t = threadIdx.x;
  int v = (t < 391) ? bsum[t] : 0;
  sh[t] = v;
  __syncthreads();
  for (int off = 1; off < 512; off <<= 1) {
    int u = (t >= off) ? sh[t - off] : 0;
    __syncthreads();
    sh[t] += u;
    __syncthreads();
  }
  if (t < 391) bsum[t] = sh[t] - v;  // exclusive
  if (t == 0) rowptr[NN] = NE;
}

// CSR build step 4: rowptr[i] = bsum[block] + exclusive-scan-within-block.
__global__ __launch_bounds__(256) void k_scan3(const int* __restrict__ deg,
                                               const int* __restrict__ bsum,
                                               int* __restrict__ rowptr) {
  __shared__ int sh[256];
  int i = blockIdx.x * 256 + threadIdx.x;
  int v = (i < NN) ? deg[i] : 0;
  sh[threadIdx.x] = v;
  __syncthreads();
  for (int off = 1; off < 256; off <<= 1) {
    int t = (threadIdx.x >= off) ? sh[threadIdx.x - off] : 0;
    __syncthreads();
    sh[threadIdx.x] += t;
    __syncthreads();
  }
  if (i < NN) rowptr[i] = bsum[blockIdx.x] + sh[threadIdx.x] - v;
}

// CSR build step 4b: cursor = rowptr (coalesced), so k_fill needs no rowptr load.
__global__ __launch_bounds__(256) void k_copy(const int* __restrict__ rowptr,
                                              int* __restrict__ cursor) {
  int i = blockIdx.x * 256 + threadIdx.x;
  if (i < NN) cursor[i] = rowptr[i];
}

// CSR build step 5: place src of each edge into its dst's row segment.
__global__ __launch_bounds__(256) void k_fill(const int* __restrict__ src,
                                              const int* __restrict__ dst,
                                              int* __restrict__ cursor,
                                              int* __restrict__ csr) {
  int e = blockIdx.x * 256 + threadIdx.x;  // NE exact
  int p = atomicAdd(&cursor[dst[e]], 1);
  csr[p] = src[e];
}

// ---------------------------------------------------------------------------
// agg[n] = (1+eps) * pre(x[n]) + sum_{s in N(n)} pre(x[s]); output bf16.
// MODE 0: f32 input, pre=identity. MODE 1: bf16 input, pre=BN1 affine.
// 4-wide unrolled neighbor loop, 4 independent accumulators.
template <int MODE>
__global__ __launch_bounds__(256) void k_gather(const float* __restrict__ xf,
                                                const unsigned short* __restrict__ xb,
                                                const int* __restrict__ rowptr,
                                                const int* __restrict__ csr,
                                                const float* __restrict__ eps,
                                                const float* __restrict__ AB,
                                                unsigned short* __restrict__ agg) {
  int f = threadIdx.x & 63;
  int n = blockIdx.x * 4 + (threadIdx.x >> 6);  // 25000*4 = NN exact
  float A = 1.0f, Bv = 0.0f;
  if (MODE) { A = AB[f]; Bv = AB[64 + f]; }
  float self = MODE ? bf2f(xb[n * 64 + f]) : xf[n * 64 + f];
  if (MODE) self = fmaf(self, A, Bv);
  float a0 = (1.0f + eps[0]) * self, a1 = 0.0f, a2 = 0.0f, a3 = 0.0f;
  int j = rowptr[n], end = rowptr[n + 1];
  while (j < end && (j & 3)) {
    int s = csr[j++];
    float v = MODE ? bf2f(xb[s * 64 + f]) : xf[s * 64 + f];
    a0 += MODE ? fmaf(v, A, Bv) : v;
  }
  const int4* c4 = (const int4*)csr;
  for (; j + 4 <= end; j += 4) {
    int4 s4 = c4[j >> 2];
    float v0 = MODE ? bf2f(xb[s4.x * 64 + f]) : xf[s4.x * 64 + f];
    float v1 = MODE ? bf2f(xb[s4.y * 64 + f]) : xf[s4.y * 64 + f];
    float v2 = MODE ? bf2f(xb[s4.z * 64 + f]) : xf[s4.z * 64 + f];
    float v3 = MODE ? bf2f(xb[s4.w * 64 + f]) : xf[s4.w * 64 + f];
    a0 += MODE ? fmaf(v0, A, Bv) : v0;
    a1 += MODE ? fmaf(v1, A, Bv) : v1;
    a2 += MODE ? fmaf(v2, A, Bv) : v2;
    a3 += MODE ? fmaf(v3, A, Bv) : v3;
  }
  for (; j < end; j++) {
    int s = csr[j];
    float v = MODE ? bf2f(xb[s * 64 + f]) : xf[s * 64 + f];
    a0 += MODE ? fmaf(v, A, Bv) : v;
  }
  agg[n * 64 + f] = f2bf((a0 + a1) + (a2 + a3));
}

// ---------------------------------------------------------------------------
// h2 = relu(relu(agg@Wa+ba)@Wb+bb) via bf16 MFMA 16x16x32; BN stats to f64.
// One wave per 16-row tile (grid-stride). Layouts (m89/m120-verified):
//   A: lane holds A[m=lane&15][k=quad*8+j], j=0..7 (short8)
//   B: lane holds B[k=quad*8+j][n=lane&15]
//   C/D: lane holds col=lane&15, rows quad*4+reg, reg=0..3 (float4)
__global__ __launch_bounds__(256) void k_mlp_mfma(
    const unsigned short* __restrict__ agg, const unsigned short* __restrict__ Wab,
    const float* __restrict__ ba, const float* __restrict__ bb,
    unsigned short* __restrict__ h2, double* __restrict__ stats) {
  const int l = threadIdx.x & 63;
  const int wv = threadIdx.x >> 6;
  const int l16 = l & 15, quad = l >> 4;

  // Weight fragments: wf[layer][coltile][kfrag]
  short8 wfa[4][2], wfb[4][2];
#pragma unroll
  for (int c = 0; c < 4; c++)
#pragma unroll
    for (int t = 0; t < 2; t++)
#pragma unroll
      for (int j = 0; j < 8; j++) {
        int k = t * 32 + quad * 8 + j, nn = c * 16 + l16;
        wfa[c][t][j] = (short)Wab[k * 64 + nn];
        wfb[c][t][j] = (short)Wab[4096 + k * 64 + nn];
      }
  float bia[4], bib[4];
#pragma unroll
  for (int c = 0; c < 4; c++) { bia[c] = ba[c * 16 + l16]; bib[c] = bb[c * 16 + l16]; }

  __shared__ float Hs[4][16][68];  // wave-private relu-intermediate tile, pad 68
  __shared__ float sS[4][64], sQ[4][64];
  float ssum[4] = {0, 0, 0, 0}, ssq[4] = {0, 0, 0, 0};

  const int totw = gridDim.x * 4;
  for (int tile = blockIdx.x * 4 + wv; tile < NN / 16; tile += totw) {
    const int r0 = tile * 16;
    const unsigned short* ap = agg + (r0 + l16) * 64 + quad * 8;
    short8 a0 = *(const short8*)ap;
    short8 a1 = *(const short8*)(ap + 32);
    // layer A: 4 col-tiles x 2 k-frags
#pragma unroll
    for (int c = 0; c < 4; c++) {
      floatx4 acc = {0.f, 0.f, 0.f, 0.f};
      acc = __builtin_amdgcn_mfma_f32_16x16x32_bf16(a0, wfa[c][0], acc, 0, 0, 0);
      acc = __builtin_amdgcn_mfma_f32_16x16x32_bf16(a1, wfa[c][1], acc, 0, 0, 0);
#pragma unroll
      for (int r = 0; r < 4; r++)
        Hs[wv][quad * 4 + r][c * 16 + l16] = fmaxf(acc[r] + bia[c], 0.0f);
    }
    // repack relu intermediate into A-operand layout (wave-private: no barrier)
    short8 a20, a21;
#pragma unroll
    for (int j = 0; j < 8; j++) {
      a20[j] = (short)f2bf(Hs[wv][l16][quad * 8 + j]);
      a21[j] = (short)f2bf(Hs[wv][l16][32 + quad * 8 + j]);
    }
    // layer B
#pragma unroll
    for (int c = 0; c < 4; c++) {
      floatx4 acc = {0.f, 0.f, 0.f, 0.f};
      acc = __builtin_amdgcn_mfma_f32_16x16x32_bf16(a20, wfb[c][0], acc, 0, 0, 0);
      acc = __builtin_amdgcn_mfma_f32_16x16x32_bf16(a21, wfb[c][1], acc, 0, 0, 0);
#pragma unroll
      for (int r = 0; r < 4; r++) {
        float v = fmaxf(acc[r] + bib[c], 0.0f);
        h2[(r0 + quad * 4 + r) * 64 + c * 16 + l16] = f2bf(v);
        ssum[c] += v;
        ssq[c] += v * v;
      }
    }
  }
  // stats: reduce over quads (same feature), then block LDS, then f64 atomics
#pragma unroll
  for (int c = 0; c < 4; c++) {
    float s = ssum[c], q = ssq[c];
    s += __shfl_xor(s, 16, 64); s += __shfl_xor(s, 32, 64);
    q += __shfl_xor(q, 16, 64); q += __shfl_xor(q, 32, 64);
    if (quad == 0) { sS[wv][c * 16 + l16] = s; sQ[wv][c * 16 + l16] = q; }
  }
  __syncthreads();
  if (threadIdx.x < 64) {
    int ff = threadIdx.x;
    float s = sS[0][ff] + sS[1][ff] + sS[2][ff] + sS[3][ff];
    float q = sQ[0][ff] + sQ[1][ff] + sQ[2][ff] + sQ[3][ff];
    unsafeAtomicAdd(&stats[ff], (double)s);
    unsafeAtomicAdd(&stats[64 + ff], (double)q);
  }
}

// ---------------------------------------------------------------------------
// stats -> per-feature affine A (scale), B (shift): out = h*A + B
__global__ void k_bnfin(const double* __restrict__ stats, const float* __restrict__ gam,
                        const float* __restrict__ bet, float* __restrict__ AB) {
  int f = threadIdx.x;  // 64 threads
  double mean = stats[f] * (1.0 / NN);
  double var = stats[64 + f] * (1.0 / NN) - mean * mean;
  if (var < 0.0) var = 0.0;
  float rstd = (float)(1.0 / sqrt(var + 1e-5));
  float A = gam[f] * rstd;
  float B = bet[f] - (float)mean * A;
  AB[f] = A;
  AB[64 + f] = B;
}

// ---------------------------------------------------------------------------
// h = BN2(h2); out[0:N*64] = h; out[N*64:] = log_softmax(h) per row.
__global__ __launch_bounds__(256) void k_out(const unsigned short* __restrict__ h2,
                                             const float* __restrict__ AB,
                                             float* __restrict__ out) {
  int f = threadIdx.x & 63;
  int n = blockIdx.x * 4 + (threadIdx.x >> 6);  // 25000*4 = NN exact
  float v = bf2f(h2[n * 64 + f]);
  float h = fmaf(v, AB[f], AB[64 + f]);
  float m = h;
#pragma unroll
  for (int off = 32; off; off >>= 1) m = fmaxf(m, __shfl_xor(m, off, 64));
  float e = expf(h - m);
  float ssum = e;
#pragma unroll
  for (int off = 32; off; off >>= 1) ssum += __shfl_xor(ssum, off, 64);
  float lsm = (h - m) - logf(ssum);
  out[n * 64 + f] = h;
  out[(size_t)NN * 64 + n * 64 + f] = lsm;
}

// ---------------------------------------------------------------------------
extern "C" void kernel_launch(void* const* d_in, const int* in_sizes, int n_in,
                              void* d_out, int out_size, void* d_ws, size_t ws_size,
                              hipStream_t stream) {
  const float* x = (const float*)d_in[0];
  const int* ei = (const int*)d_in[1];  // [2, E] as int32
  const float* W1 = (const float*)d_in[2];
  const float* b1 = (const float*)d_in[3];
  const float* W2 = (const float*)d_in[4];
  const float* b2 = (const float*)d_in[5];
  const float* g1 = (const float*)d_in[6];
  const float* bt1 = (const float*)d_in[7];
  const float* e1 = (const float*)d_in[8];
  const float* W3 = (const float*)d_in[9];
  const float* b3 = (const float*)d_in[10];
  const float* W4 = (const float*)d_in[11];
  const float* b4 = (const float*)d_in[12];
  const float* g2 = (const float*)d_in[13];
  const float* bt2 = (const float*)d_in[14];
  const float* e2 = (const float*)d_in[15];
  const int* src = ei;
  const int* dst = ei + NE;

  char* ws = (char*)d_ws;
  unsigned short* aggb = (unsigned short*)(ws);             // 12.8 MB bf16
  unsigned short* h2b = (unsigned short*)(ws + 12800000);   // 12.8 MB bf16
  int* rowptr = (int*)(ws + 25600000);                      // 100001 ints
  int* tmp = (int*)(ws + 26000128);                         // 100000 ints (deg/cursor)
  int* csr = (int*)(ws + 26400256);                         // 1.6M ints, 16B-aligned
  int* bsum = (int*)(ws + 32800256);                        // 512 ints
  double* st1 = (double*)(ws + 32802304);                   // 128 f64
  double* st2 = (double*)(ws + 32803328);                   // 128 f64
  float* AB1 = (float*)(ws + 32804352);                     // 128 f32
  float* AB2 = (float*)(ws + 32804864);                     // 128 f32
  unsigned short* Wbb = (unsigned short*)(ws + 32805376);   // 4*4096 bf16
  float* out = (float*)d_out;

  hipMemsetAsync(ws + 32802304, 0, 2048, stream);  // zero st1+st2
  hipMemsetAsync(tmp, 0, 400000, stream);          // zero deg

  k_cvtW<<<16, 256, 0, stream>>>(W1, W2, W3, W4, Wbb);

  // --- CSR build (shared by both layers) ---
  k_hist<<<NE / 256, 256, 0, stream>>>(dst, tmp);
  k_bsum<<<391, 256, 0, stream>>>(tmp, bsum);
  k_scanB<<<1, 512, 0, stream>>>(bsum, rowptr);
  k_scan3<<<391, 256, 0, stream>>>(tmp, bsum, rowptr);
  k_copy<<<391, 256, 0, stream>>>(rowptr, tmp);  // cursor = rowptr
  k_fill<<<NE / 256, 256, 0, stream>>>(src, dst, tmp, csr);

  // --- Layer 1 ---
  k_gather<0><<<NN / 4, 256, 0, stream>>>(x, nullptr, rowptr, csr, e1, nullptr, aggb);
  k_mlp_mfma<<<391, 256, 0, stream>>>(aggb, Wbb, b1, b2, h2b, st1);
  k_bnfin<<<1, 64, 0, stream>>>(st1, g1, bt1, AB1);
  // --- Layer 2 (BN1-apply fused into the gather) ---
  k_gather<1><<<NN / 4, 256, 0, stream>>>(nullptr, h2b, rowptr, csr, e2, AB1, aggb);
  k_mlp_mfma<<<391, 256, 0, stream>>>(aggb, Wbb + 8192, b3, b4, h2b, st2);
  k_bnfin<<<1, 64, 0, stream>>>(st2, g2, bt2, AB2);
  // --- Epilogue: BN2 + log_softmax ---
  k_out<<<NN / 4, 256, 0, stream>>>(h2b, AB2, out);
}

// Round 6
// 412.558 us; speedup vs baseline: 7.1874x; 1.2375x over previous
//
#include <hip/hip_runtime.h>

#define NN 100000
#define NE 1600000

typedef __attribute__((ext_vector_type(8))) short short8;
typedef __attribute__((ext_vector_type(4))) float floatx4;

__device__ __forceinline__ unsigned short f2bf(float f) {
  unsigned u = __float_as_uint(f);
  u += 0x7fffu + ((u >> 16) & 1u);  // RNE
  return (unsigned short)(u >> 16);
}
__device__ __forceinline__ float bf2f(unsigned short b) {
  return __uint_as_float(((unsigned)b) << 16);
}

// ---------------------------------------------------------------------------
// Convert the 4 weight matrices (each 64x64 f32 row-major) to bf16.
__global__ __launch_bounds__(256) void k_cvtW(const float* __restrict__ W1,
                                              const float* __restrict__ W2,
                                              const float* __restrict__ W3,
                                              const float* __restrict__ W4,
                                              unsigned short* __restrict__ Wb) {
  int i = blockIdx.x * 256 + threadIdx.x;  // 16 blocks * 256 = 4096 exact
  Wb[i] = f2bf(W1[i]);
  Wb[4096 + i] = f2bf(W2[i]);
  Wb[8192 + i] = f2bf(W3[i]);
  Wb[12288 + i] = f2bf(W4[i]);
}

// ---------------------------------------------------------------------------
// ELL build: slot p = atomicAdd(cursor[dst]); ell[dst*64+p] = src.
// 4 edges per thread (int4 loads) -> 4 independent atomics in flight.
// Post-fill, cursor[n] == degree(n). Capacity 64: P(overflow) ~ 1e-19.
__global__ __launch_bounds__(256) void k_fill(const int4* __restrict__ src4,
                                              const int4* __restrict__ dst4,
                                              int* __restrict__ cursor,
                                              int* __restrict__ ell) {
  int t = blockIdx.x * 256 + threadIdx.x;
  if (t >= NE / 4) return;
  int4 d = dst4[t];
  int4 s = src4[t];
  int p0 = atomicAdd(&cursor[d.x], 1);
  int p1 = atomicAdd(&cursor[d.y], 1);
  int p2 = atomicAdd(&cursor[d.z], 1);
  int p3 = atomicAdd(&cursor[d.w], 1);
  if (p0 < 64) ell[d.x * 64 + p0] = s.x;
  if (p1 < 64) ell[d.y * 64 + p1] = s.y;
  if (p2 < 64) ell[d.z * 64 + p2] = s.z;
  if (p3 < 64) ell[d.w * 64 + p3] = s.w;
}

// ---------------------------------------------------------------------------
// agg[n] = (1+eps) * pre(x[n]) + sum_{s in N(n)} pre(x[s]); output bf16.
// MODE 0: f32 input, pre=identity. MODE 1: bf16 input, pre=BN1 affine.
// 32 lanes per node (2 feats/lane) -> 8 rows in flight per wave; 4-wide
// unrolled neighbor loop with independent accumulator pairs.
template <int MODE>
__global__ __launch_bounds__(256) void k_gather(const float* __restrict__ xf,
                                                const unsigned short* __restrict__ xb,
                                                const int* __restrict__ deg,
                                                const int* __restrict__ ell,
                                                const float* __restrict__ eps,
                                                const float* __restrict__ AB,
                                                unsigned short* __restrict__ agg) {
  const int lane = threadIdx.x & 31;           // feature pair id
  const int slot = threadIdx.x >> 5;           // node slot in block (0..7)
  const int n = blockIdx.x * 8 + slot;         // 12500 blocks * 8 = NN exact
  const int fo = 2 * lane;
  float A0 = 1.0f, B0 = 0.0f, A1 = 1.0f, B1 = 0.0f;
  if (MODE) { A0 = AB[fo]; B0 = AB[64 + fo]; A1 = AB[fo + 1]; B1 = AB[64 + fo + 1]; }
  float s0, s1;
  if (MODE) {
    ushort2 u = *(const ushort2*)(xb + n * 64 + fo);
    s0 = fmaf(bf2f(u.x), A0, B0);
    s1 = fmaf(bf2f(u.y), A1, B1);
  } else {
    float2 u = *(const float2*)(xf + n * 64 + fo);
    s0 = u.x;
    s1 = u.y;
  }
  const float es = 1.0f + eps[0];
  float a0 = es * s0, a1 = es * s1;
  float b0 = 0, b1 = 0, c0 = 0, c1 = 0, d0 = 0, d1 = 0;
  const int cnt = deg[n];
  const int* row = ell + n * 64;
  const int4* r4 = (const int4*)row;
  int j = 0;
  for (; j + 4 <= cnt; j += 4) {
    int4 s4 = r4[j >> 2];
    if (MODE) {
      ushort2 u0 = *(const ushort2*)(xb + s4.x * 64 + fo);
      ushort2 u1 = *(const ushort2*)(xb + s4.y * 64 + fo);
      ushort2 u2 = *(const ushort2*)(xb + s4.z * 64 + fo);
      ushort2 u3 = *(const ushort2*)(xb + s4.w * 64 + fo);
      a0 = fmaf(bf2f(u0.x), A0, a0); a1 = fmaf(bf2f(u0.y), A1, a1);
      b0 = fmaf(bf2f(u1.x), A0, b0); b1 = fmaf(bf2f(u1.y), A1, b1);
      c0 = fmaf(bf2f(u2.x), A0, c0); c1 = fmaf(bf2f(u2.y), A1, c1);
      d0 = fmaf(bf2f(u3.x), A0, d0); d1 = fmaf(bf2f(u3.y), A1, d1);
      a0 += B0; a1 += B1; b0 += B0; b1 += B1;  // add shift per neighbor
      c0 += B0; c1 += B1; d0 += B0; d1 += B1;
    } else {
      float2 u0 = *(const float2*)(xf + s4.x * 64 + fo);
      float2 u1 = *(const float2*)(xf + s4.y * 64 + fo);
      float2 u2 = *(const float2*)(xf + s4.z * 64 + fo);
      float2 u3 = *(const float2*)(xf + s4.w * 64 + fo);
      a0 += u0.x; a1 += u0.y;
      b0 += u1.x; b1 += u1.y;
      c0 += u2.x; c1 += u2.y;
      d0 += u3.x; d1 += u3.y;
    }
  }
  for (; j < cnt; j++) {
    int s = row[j];
    if (MODE) {
      ushort2 u = *(const ushort2*)(xb + s * 64 + fo);
      a0 += fmaf(bf2f(u.x), A0, B0);
      a1 += fmaf(bf2f(u.y), A1, B1);
    } else {
      float2 u = *(const float2*)(xf + s * 64 + fo);
      a0 += u.x;
      a1 += u.y;
    }
  }
  float r0 = (a0 + b0) + (c0 + d0);
  float r1 = (a1 + b1) + (c1 + d1);
  ushort2 st;
  st.x = f2bf(r0);
  st.y = f2bf(r1);
  *(ushort2*)(agg + n * 64 + fo) = st;
}

// ---------------------------------------------------------------------------
// h2 = relu(relu(agg@Wa+ba)@Wb+bb) via bf16 MFMA 16x16x32; BN stats to f64.
__global__ __launch_bounds__(256) void k_mlp_mfma(
    const unsigned short* __restrict__ agg, const unsigned short* __restrict__ Wab,
    const float* __restrict__ ba, const float* __restrict__ bb,
    unsigned short* __restrict__ h2, double* __restrict__ stats) {
  const int l = threadIdx.x & 63;
  const int wv = threadIdx.x >> 6;
  const int l16 = l & 15, quad = l >> 4;

  short8 wfa[4][2], wfb[4][2];
#pragma unroll
  for (int c = 0; c < 4; c++)
#pragma unroll
    for (int t = 0; t < 2; t++)
#pragma unroll
      for (int j = 0; j < 8; j++) {
        int k = t * 32 + quad * 8 + j, nn = c * 16 + l16;
        wfa[c][t][j] = (short)Wab[k * 64 + nn];
        wfb[c][t][j] = (short)Wab[4096 + k * 64 + nn];
      }
  float bia[4], bib[4];
#pragma unroll
  for (int c = 0; c < 4; c++) { bia[c] = ba[c * 16 + l16]; bib[c] = bb[c * 16 + l16]; }

  __shared__ float Hs[4][16][68];
  __shared__ float sS[4][64], sQ[4][64];
  float ssum[4] = {0, 0, 0, 0}, ssq[4] = {0, 0, 0, 0};

  const int totw = gridDim.x * 4;
  for (int tile = blockIdx.x * 4 + wv; tile < NN / 16; tile += totw) {
    const int r0 = tile * 16;
    const unsigned short* ap = agg + (r0 + l16) * 64 + quad * 8;
    short8 a0 = *(const short8*)ap;
    short8 a1 = *(const short8*)(ap + 32);
#pragma unroll
    for (int c = 0; c < 4; c++) {
      floatx4 acc = {0.f, 0.f, 0.f, 0.f};
      acc = __builtin_amdgcn_mfma_f32_16x16x32_bf16(a0, wfa[c][0], acc, 0, 0, 0);
      acc = __builtin_amdgcn_mfma_f32_16x16x32_bf16(a1, wfa[c][1], acc, 0, 0, 0);
#pragma unroll
      for (int r = 0; r < 4; r++)
        Hs[wv][quad * 4 + r][c * 16 + l16] = fmaxf(acc[r] + bia[c], 0.0f);
    }
    short8 a20, a21;
#pragma unroll
    for (int j = 0; j < 8; j++) {
      a20[j] = (short)f2bf(Hs[wv][l16][quad * 8 + j]);
      a21[j] = (short)f2bf(Hs[wv][l16][32 + quad * 8 + j]);
    }
#pragma unroll
    for (int c = 0; c < 4; c++) {
      floatx4 acc = {0.f, 0.f, 0.f, 0.f};
      acc = __builtin_amdgcn_mfma_f32_16x16x32_bf16(a20, wfb[c][0], acc, 0, 0, 0);
      acc = __builtin_amdgcn_mfma_f32_16x16x32_bf16(a21, wfb[c][1], acc, 0, 0, 0);
#pragma unroll
      for (int r = 0; r < 4; r++) {
        float v = fmaxf(acc[r] + bib[c], 0.0f);
        h2[(r0 + quad * 4 + r) * 64 + c * 16 + l16] = f2bf(v);
        ssum[c] += v;
        ssq[c] += v * v;
      }
    }
  }
#pragma unroll
  for (int c = 0; c < 4; c++) {
    float s = ssum[c], q = ssq[c];
    s += __shfl_xor(s, 16, 64); s += __shfl_xor(s, 32, 64);
    q += __shfl_xor(q, 16, 64); q += __shfl_xor(q, 32, 64);
    if (quad == 0) { sS[wv][c * 16 + l16] = s; sQ[wv][c * 16 + l16] = q; }
  }
  __syncthreads();
  if (threadIdx.x < 64) {
    int ff = threadIdx.x;
    float s = sS[0][ff] + sS[1][ff] + sS[2][ff] + sS[3][ff];
    float q = sQ[0][ff] + sQ[1][ff] + sQ[2][ff] + sQ[3][ff];
    unsafeAtomicAdd(&stats[ff], (double)s);
    unsafeAtomicAdd(&stats[64 + ff], (double)q);
  }
}

// ---------------------------------------------------------------------------
// stats -> per-feature affine A (scale), B (shift): out = h*A + B
__global__ void k_bnfin(const double* __restrict__ stats, const float* __restrict__ gam,
                        const float* __restrict__ bet, float* __restrict__ AB) {
  int f = threadIdx.x;  // 64 threads
  double mean = stats[f] * (1.0 / NN);
  double var = stats[64 + f] * (1.0 / NN) - mean * mean;
  if (var < 0.0) var = 0.0;
  float rstd = (float)(1.0 / sqrt(var + 1e-5));
  float A = gam[f] * rstd;
  float B = bet[f] - (float)mean * A;
  AB[f] = A;
  AB[64 + f] = B;
}

// ---------------------------------------------------------------------------
// h = BN2(h2); out[0:N*64] = h; out[N*64:] = log_softmax(h) per row.
__global__ __launch_bounds__(256) void k_out(const unsigned short* __restrict__ h2,
                                             const float* __restrict__ AB,
                                             float* __restrict__ out) {
  int f = threadIdx.x & 63;
  int n = blockIdx.x * 4 + (threadIdx.x >> 6);  // 25000*4 = NN exact
  float v = bf2f(h2[n * 64 + f]);
  float h = fmaf(v, AB[f], AB[64 + f]);
  float m = h;
#pragma unroll
  for (int off = 32; off; off >>= 1) m = fmaxf(m, __shfl_xor(m, off, 64));
  float e = expf(h - m);
  float ssum = e;
#pragma unroll
  for (int off = 32; off; off >>= 1) ssum += __shfl_xor(ssum, off, 64);
  float lsm = (h - m) - logf(ssum);
  out[n * 64 + f] = h;
  out[(size_t)NN * 64 + n * 64 + f] = lsm;
}

// ---------------------------------------------------------------------------
extern "C" void kernel_launch(void* const* d_in, const int* in_sizes, int n_in,
                              void* d_out, int out_size, void* d_ws, size_t ws_size,
                              hipStream_t stream) {
  const float* x = (const float*)d_in[0];
  const int* ei = (const int*)d_in[1];  // [2, E] as int32
  const float* W1 = (const float*)d_in[2];
  const float* b1 = (const float*)d_in[3];
  const float* W2 = (const float*)d_in[4];
  const float* b2 = (const float*)d_in[5];
  const float* g1 = (const float*)d_in[6];
  const float* bt1 = (const float*)d_in[7];
  const float* e1 = (const float*)d_in[8];
  const float* W3 = (const float*)d_in[9];
  const float* b3 = (const float*)d_in[10];
  const float* W4 = (const float*)d_in[11];
  const float* b4 = (const float*)d_in[12];
  const float* g2 = (const float*)d_in[13];
  const float* bt2 = (const float*)d_in[14];
  const float* e2 = (const float*)d_in[15];
  const int4* src4 = (const int4*)ei;
  const int4* dst4 = (const int4*)(ei + NE);

  char* ws = (char*)d_ws;
  unsigned short* aggb = (unsigned short*)(ws);             // 12.8 MB bf16
  unsigned short* h2b = (unsigned short*)(ws + 12800000);   // 12.8 MB bf16
  int* ell = (int*)(ws + 25600000);                         // 100000*64 ints = 25.6 MB
  int* cursor = (int*)(ws + 51200000);                      // 100000 ints (deg after fill)
  double* st1 = (double*)(ws + 51600000);                   // 128 f64
  double* st2 = (double*)(ws + 51601024);                   // 128 f64
  float* AB1 = (float*)(ws + 51602048);                     // 128 f32
  float* AB2 = (float*)(ws + 51602560);                     // 128 f32
  unsigned short* Wbb = (unsigned short*)(ws + 51603072);   // 4*4096 bf16
  float* out = (float*)d_out;

  hipMemsetAsync(ws + 51600000, 0, 2048, stream);  // zero st1+st2
  hipMemsetAsync(cursor, 0, 400000, stream);       // zero cursors

  k_cvtW<<<16, 256, 0, stream>>>(W1, W2, W3, W4, Wbb);

  // --- ELL build (shared by both layers); cursor becomes degree ---
  k_fill<<<(NE / 4 + 255) / 256, 256, 0, stream>>>(src4, dst4, cursor, ell);

  // --- Layer 1 ---
  k_gather<0><<<NN / 8, 256, 0, stream>>>(x, nullptr, cursor, ell, e1, nullptr, aggb);
  k_mlp_mfma<<<391, 256, 0, stream>>>(aggb, Wbb, b1, b2, h2b, st1);
  k_bnfin<<<1, 64, 0, stream>>>(st1, g1, bt1, AB1);
  // --- Layer 2 (BN1-apply fused into the gather) ---
  k_gather<1><<<NN / 8, 256, 0, stream>>>(nullptr, h2b, cursor, ell, e2, AB1, aggb);
  k_mlp_mfma<<<391, 256, 0, stream>>>(aggb, Wbb + 8192, b3, b4, h2b, st2);
  k_bnfin<<<1, 64, 0, stream>>>(st2, g2, bt2, AB2);
  // --- Epilogue: BN2 + log_softmax ---
  k_out<<<NN / 4, 256, 0, stream>>>(h2b, AB2, out);
}

// Round 7
// 389.189 us; speedup vs baseline: 7.6190x; 1.0600x over previous
//
#include <hip/hip_runtime.h>

#define NN 100000
#define NE 1600000

typedef __attribute__((ext_vector_type(8))) short short8;
typedef __attribute__((ext_vector_type(4))) float floatx4;

__device__ __forceinline__ unsigned short f2bf(float f) {
  unsigned u = __float_as_uint(f);
  u += 0x7fffu + ((u >> 16) & 1u);  // RNE
  return (unsigned short)(u >> 16);
}
__device__ __forceinline__ float bf2f(unsigned short b) {
  return __uint_as_float(((unsigned)b) << 16);
}

// ---------------------------------------------------------------------------
// Convert the 4 weight matrices (each 64x64 f32 row-major) to bf16.
__global__ __launch_bounds__(256) void k_cvtW(const float* __restrict__ W1,
                                              const float* __restrict__ W2,
                                              const float* __restrict__ W3,
                                              const float* __restrict__ W4,
                                              unsigned short* __restrict__ Wb) {
  int i = blockIdx.x * 256 + threadIdx.x;  // 16 blocks * 256 = 4096 exact
  Wb[i] = f2bf(W1[i]);
  Wb[4096 + i] = f2bf(W2[i]);
  Wb[8192 + i] = f2bf(W3[i]);
  Wb[12288 + i] = f2bf(W4[i]);
}

// ---------------------------------------------------------------------------
// ELL build: slot p = atomicAdd(cursor[dst*16]); ell[dst*64+p] = src.
// Cursors PADDED to one per 64B cache line: the coherence point serializes
// with-return RMWs per line, so unpadded cursors made ~256 edges contend per
// line (16 cursors/line x deg 16). 1 edge/thread for max streams in flight.
// Post-fill, cursor[n*16] == degree(n). Capacity 64: P(overflow) ~ 1e-19.
__global__ __launch_bounds__(256) void k_fill(const int* __restrict__ src,
                                              const int* __restrict__ dst,
                                              int* __restrict__ cursor,
                                              int* __restrict__ ell) {
  int e = blockIdx.x * 256 + threadIdx.x;  // NE exact (6250*256)
  int d = dst[e];
  int p = atomicAdd(&cursor[d * 16], 1);
  if (p < 64) ell[d * 64 + p] = src[e];
}

// ---------------------------------------------------------------------------
// agg[n] = (1+eps) * pre(x[n]) + sum_{s in N(n)} pre(x[s]); output bf16.
// MODE 0: f32 input, pre=identity. MODE 1: bf16 input, pre=BN1 affine.
// 32 lanes per node (2 feats/lane) -> 8 rows in flight per wave; 4-wide
// unrolled neighbor loop with independent accumulator pairs.
template <int MODE>
__global__ __launch_bounds__(256) void k_gather(const float* __restrict__ xf,
                                                const unsigned short* __restrict__ xb,
                                                const int* __restrict__ deg16,
                                                const int* __restrict__ ell,
                                                const float* __restrict__ eps,
                                                const float* __restrict__ AB,
                                                unsigned short* __restrict__ agg) {
  const int lane = threadIdx.x & 31;           // feature pair id
  const int slot = threadIdx.x >> 5;           // node slot in block (0..7)
  const int n = blockIdx.x * 8 + slot;         // 12500 blocks * 8 = NN exact
  const int fo = 2 * lane;
  float A0 = 1.0f, B0 = 0.0f, A1 = 1.0f, B1 = 0.0f;
  if (MODE) { A0 = AB[fo]; B0 = AB[64 + fo]; A1 = AB[fo + 1]; B1 = AB[64 + fo + 1]; }
  float s0, s1;
  if (MODE) {
    ushort2 u = *(const ushort2*)(xb + n * 64 + fo);
    s0 = fmaf(bf2f(u.x), A0, B0);
    s1 = fmaf(bf2f(u.y), A1, B1);
  } else {
    float2 u = *(const float2*)(xf + n * 64 + fo);
    s0 = u.x;
    s1 = u.y;
  }
  const float es = 1.0f + eps[0];
  float a0 = es * s0, a1 = es * s1;
  float b0 = 0, b1 = 0, c0 = 0, c1 = 0, d0 = 0, d1 = 0;
  const int cnt = deg16[n * 16];
  const int* row = ell + n * 64;
  const int4* r4 = (const int4*)row;
  int j = 0;
  for (; j + 4 <= cnt; j += 4) {
    int4 s4 = r4[j >> 2];
    if (MODE) {
      ushort2 u0 = *(const ushort2*)(xb + s4.x * 64 + fo);
      ushort2 u1 = *(const ushort2*)(xb + s4.y * 64 + fo);
      ushort2 u2 = *(const ushort2*)(xb + s4.z * 64 + fo);
      ushort2 u3 = *(const ushort2*)(xb + s4.w * 64 + fo);
      a0 = fmaf(bf2f(u0.x), A0, a0); a1 = fmaf(bf2f(u0.y), A1, a1);
      b0 = fmaf(bf2f(u1.x), A0, b0); b1 = fmaf(bf2f(u1.y), A1, b1);
      c0 = fmaf(bf2f(u2.x), A0, c0); c1 = fmaf(bf2f(u2.y), A1, c1);
      d0 = fmaf(bf2f(u3.x), A0, d0); d1 = fmaf(bf2f(u3.y), A1, d1);
      a0 += B0; a1 += B1; b0 += B0; b1 += B1;  // add shift per neighbor
      c0 += B0; c1 += B1; d0 += B0; d1 += B1;
    } else {
      float2 u0 = *(const float2*)(xf + s4.x * 64 + fo);
      float2 u1 = *(const float2*)(xf + s4.y * 64 + fo);
      float2 u2 = *(const float2*)(xf + s4.z * 64 + fo);
      float2 u3 = *(const float2*)(xf + s4.w * 64 + fo);
      a0 += u0.x; a1 += u0.y;
      b0 += u1.x; b1 += u1.y;
      c0 += u2.x; c1 += u2.y;
      d0 += u3.x; d1 += u3.y;
    }
  }
  for (; j < cnt; j++) {
    int s = row[j];
    if (MODE) {
      ushort2 u = *(const ushort2*)(xb + s * 64 + fo);
      a0 += fmaf(bf2f(u.x), A0, B0);
      a1 += fmaf(bf2f(u.y), A1, B1);
    } else {
      float2 u = *(const float2*)(xf + s * 64 + fo);
      a0 += u.x;
      a1 += u.y;
    }
  }
  float r0 = (a0 + b0) + (c0 + d0);
  float r1 = (a1 + b1) + (c1 + d1);
  ushort2 st;
  st.x = f2bf(r0);
  st.y = f2bf(r1);
  *(ushort2*)(agg + n * 64 + fo) = st;
}

// ---------------------------------------------------------------------------
// h2 = relu(relu(agg@Wa+ba)@Wb+bb) via bf16 MFMA 16x16x32; BN stats to f64.
__global__ __launch_bounds__(256) void k_mlp_mfma(
    const unsigned short* __restrict__ agg, const unsigned short* __restrict__ Wab,
    const float* __restrict__ ba, const float* __restrict__ bb,
    unsigned short* __restrict__ h2, double* __restrict__ stats) {
  const int l = threadIdx.x & 63;
  const int wv = threadIdx.x >> 6;
  const int l16 = l & 15, quad = l >> 4;

  short8 wfa[4][2], wfb[4][2];
#pragma unroll
  for (int c = 0; c < 4; c++)
#pragma unroll
    for (int t = 0; t < 2; t++)
#pragma unroll
      for (int j = 0; j < 8; j++) {
        int k = t * 32 + quad * 8 + j, nn = c * 16 + l16;
        wfa[c][t][j] = (short)Wab[k * 64 + nn];
        wfb[c][t][j] = (short)Wab[4096 + k * 64 + nn];
      }
  float bia[4], bib[4];
#pragma unroll
  for (int c = 0; c < 4; c++) { bia[c] = ba[c * 16 + l16]; bib[c] = bb[c * 16 + l16]; }

  __shared__ float Hs[4][16][68];
  __shared__ float sS[4][64], sQ[4][64];
  float ssum[4] = {0, 0, 0, 0}, ssq[4] = {0, 0, 0, 0};

  const int totw = gridDim.x * 4;
  for (int tile = blockIdx.x * 4 + wv; tile < NN / 16; tile += totw) {
    const int r0 = tile * 16;
    const unsigned short* ap = agg + (r0 + l16) * 64 + quad * 8;
    short8 a0 = *(const short8*)ap;
    short8 a1 = *(const short8*)(ap + 32);
#pragma unroll
    for (int c = 0; c < 4; c++) {
      floatx4 acc = {0.f, 0.f, 0.f, 0.f};
      acc = __builtin_amdgcn_mfma_f32_16x16x32_bf16(a0, wfa[c][0], acc, 0, 0, 0);
      acc = __builtin_amdgcn_mfma_f32_16x16x32_bf16(a1, wfa[c][1], acc, 0, 0, 0);
#pragma unroll
      for (int r = 0; r < 4; r++)
        Hs[wv][quad * 4 + r][c * 16 + l16] = fmaxf(acc[r] + bia[c], 0.0f);
    }
    short8 a20, a21;
#pragma unroll
    for (int j = 0; j < 8; j++) {
      a20[j] = (short)f2bf(Hs[wv][l16][quad * 8 + j]);
      a21[j] = (short)f2bf(Hs[wv][l16][32 + quad * 8 + j]);
    }
#pragma unroll
    for (int c = 0; c < 4; c++) {
      floatx4 acc = {0.f, 0.f, 0.f, 0.f};
      acc = __builtin_amdgcn_mfma_f32_16x16x32_bf16(a20, wfb[c][0], acc, 0, 0, 0);
      acc = __builtin_amdgcn_mfma_f32_16x16x32_bf16(a21, wfb[c][1], acc, 0, 0, 0);
#pragma unroll
      for (int r = 0; r < 4; r++) {
        float v = fmaxf(acc[r] + bib[c], 0.0f);
        h2[(r0 + quad * 4 + r) * 64 + c * 16 + l16] = f2bf(v);
        ssum[c] += v;
        ssq[c] += v * v;
      }
    }
  }
#pragma unroll
  for (int c = 0; c < 4; c++) {
    float s = ssum[c], q = ssq[c];
    s += __shfl_xor(s, 16, 64); s += __shfl_xor(s, 32, 64);
    q += __shfl_xor(q, 16, 64); q += __shfl_xor(q, 32, 64);
    if (quad == 0) { sS[wv][c * 16 + l16] = s; sQ[wv][c * 16 + l16] = q; }
  }
  __syncthreads();
  if (threadIdx.x < 64) {
    int ff = threadIdx.x;
    float s = sS[0][ff] + sS[1][ff] + sS[2][ff] + sS[3][ff];
    float q = sQ[0][ff] + sQ[1][ff] + sQ[2][ff] + sQ[3][ff];
    unsafeAtomicAdd(&stats[ff], (double)s);
    unsafeAtomicAdd(&stats[64 + ff], (double)q);
  }
}

// ---------------------------------------------------------------------------
// stats -> per-feature affine A (scale), B (shift): out = h*A + B
__global__ void k_bnfin(const double* __restrict__ stats, const float* __restrict__ gam,
                        const float* __restrict__ bet, float* __restrict__ AB) {
  int f = threadIdx.x;  // 64 threads
  double mean = stats[f] * (1.0 / NN);
  double var = stats[64 + f] * (1.0 / NN) - mean * mean;
  if (var < 0.0) var = 0.0;
  float rstd = (float)(1.0 / sqrt(var + 1e-5));
  float A = gam[f] * rstd;
  float B = bet[f] - (float)mean * A;
  AB[f] = A;
  AB[64 + f] = B;
}

// ---------------------------------------------------------------------------
// h = BN2(h2); out[0:N*64] = h; out[N*64:] = log_softmax(h) per row.
__global__ __launch_bounds__(256) void k_out(const unsigned short* __restrict__ h2,
                                             const float* __restrict__ AB,
                                             float* __restrict__ out) {
  int f = threadIdx.x & 63;
  int n = blockIdx.x * 4 + (threadIdx.x >> 6);  // 25000*4 = NN exact
  float v = bf2f(h2[n * 64 + f]);
  float h = fmaf(v, AB[f], AB[64 + f]);
  float m = h;
#pragma unroll
  for (int off = 32; off; off >>= 1) m = fmaxf(m, __shfl_xor(m, off, 64));
  float e = expf(h - m);
  float ssum = e;
#pragma unroll
  for (int off = 32; off; off >>= 1) ssum += __shfl_xor(ssum, off, 64);
  float lsm = (h - m) - logf(ssum);
  out[n * 64 + f] = h;
  out[(size_t)NN * 64 + n * 64 + f] = lsm;
}

// ---------------------------------------------------------------------------
extern "C" void kernel_launch(void* const* d_in, const int* in_sizes, int n_in,
                              void* d_out, int out_size, void* d_ws, size_t ws_size,
                              hipStream_t stream) {
  const float* x = (const float*)d_in[0];
  const int* ei = (const int*)d_in[1];  // [2, E] as int32
  const float* W1 = (const float*)d_in[2];
  const float* b1 = (const float*)d_in[3];
  const float* W2 = (const float*)d_in[4];
  const float* b2 = (const float*)d_in[5];
  const float* g1 = (const float*)d_in[6];
  const float* bt1 = (const float*)d_in[7];
  const float* e1 = (const float*)d_in[8];
  const float* W3 = (const float*)d_in[9];
  const float* b3 = (const float*)d_in[10];
  const float* W4 = (const float*)d_in[11];
  const float* b4 = (const float*)d_in[12];
  const float* g2 = (const float*)d_in[13];
  const float* bt2 = (const float*)d_in[14];
  const float* e2 = (const float*)d_in[15];
  const int* src = ei;
  const int* dst = ei + NE;

  char* ws = (char*)d_ws;
  unsigned short* aggb = (unsigned short*)(ws);             // 12.8 MB bf16
  unsigned short* h2b = (unsigned short*)(ws + 12800000);   // 12.8 MB bf16
  int* ell = (int*)(ws + 25600000);                         // 100000*64 ints = 25.6 MB
  int* cursor = (int*)(ws + 51200000);                      // 100000*16 ints = 6.4 MB (line-padded)
  double* st1 = (double*)(ws + 57600000);                   // 128 f64
  double* st2 = (double*)(ws + 57601024);                   // 128 f64
  float* AB1 = (float*)(ws + 57602048);                     // 128 f32
  float* AB2 = (float*)(ws + 57602560);                     // 128 f32
  unsigned short* Wbb = (unsigned short*)(ws + 57603072);   // 4*4096 bf16
  float* out = (float*)d_out;

  hipMemsetAsync(ws + 57600000, 0, 2048, stream);  // zero st1+st2
  hipMemsetAsync(cursor, 0, 6400000, stream);      // zero padded cursors

  k_cvtW<<<16, 256, 0, stream>>>(W1, W2, W3, W4, Wbb);

  // --- ELL build (shared by both layers); cursor[n*16] becomes degree ---
  k_fill<<<NE / 256, 256, 0, stream>>>(src, dst, cursor, ell);

  // --- Layer 1 ---
  k_gather<0><<<NN / 8, 256, 0, stream>>>(x, nullptr, cursor, ell, e1, nullptr, aggb);
  k_mlp_mfma<<<391, 256, 0, stream>>>(aggb, Wbb, b1, b2, h2b, st1);
  k_bnfin<<<1, 64, 0, stream>>>(st1, g1, bt1, AB1);
  // --- Layer 2 (BN1-apply fused into the gather) ---
  k_gather<1><<<NN / 8, 256, 0, stream>>>(nullptr, h2b, cursor, ell, e2, AB1, aggb);
  k_mlp_mfma<<<391, 256, 0, stream>>>(aggb, Wbb + 8192, b3, b4, h2b, st2);
  k_bnfin<<<1, 64, 0, stream>>>(st2, g2, bt2, AB2);
  // --- Epilogue: BN2 + log_softmax ---
  k_out<<<NN / 4, 256, 0, stream>>>(h2b, AB2, out);
}

// Round 8
// 317.200 us; speedup vs baseline: 9.3481x; 1.2270x over previous
//
#include <hip/hip_runtime.h>

#define NN 100000
#define NE 1600000
#define NB 256   // dst buckets
#define BSZ 391  // nodes per bucket (255*391=99705; bucket 255 holds 295)
#define EB 782   // edge blocks of 2048 (782*2048 >= NE)

typedef __attribute__((ext_vector_type(8))) short short8;
typedef __attribute__((ext_vector_type(4))) float floatx4;

__device__ __forceinline__ unsigned short f2bf(float f) {
  unsigned u = __float_as_uint(f);
  u += 0x7fffu + ((u >> 16) & 1u);  // RNE
  return (unsigned short)(u >> 16);
}
__device__ __forceinline__ float bf2f(unsigned short b) {
  return __uint_as_float(((unsigned)b) << 16);
}

// ---------------------------------------------------------------------------
// Convert the 4 weight matrices (each 64x64 f32 row-major) to bf16.
__global__ __launch_bounds__(256) void k_cvtW(const float* __restrict__ W1,
                                              const float* __restrict__ W2,
                                              const float* __restrict__ W3,
                                              const float* __restrict__ W4,
                                              unsigned short* __restrict__ Wb) {
  int i = blockIdx.x * 256 + threadIdx.x;  // 16 blocks * 256 = 4096 exact
  Wb[i] = f2bf(W1[i]);
  Wb[4096 + i] = f2bf(W2[i]);
  Wb[8192 + i] = f2bf(W3[i]);
  Wb[12288 + i] = f2bf(W4[i]);
}

// ---------------------------------------------------------------------------
// ELL build via bucket partition — NO global atomics (only LDS).
// Pass 1: per-(block,bucket) histogram.
__global__ __launch_bounds__(256) void k_phist(const int* __restrict__ dst,
                                               int* __restrict__ blockHist) {
  __shared__ int h[NB];
  h[threadIdx.x] = 0;
  __syncthreads();
  int base = blockIdx.x * 2048;
#pragma unroll
  for (int i = 0; i < 8; i++) {
    int e = base + i * 256 + threadIdx.x;
    if (e < NE) atomicAdd(&h[dst[e] / BSZ], 1);
  }
  __syncthreads();
  blockHist[blockIdx.x * NB + threadIdx.x] = h[threadIdx.x];
}

// Pass 2: per-bucket exclusive scan over the EB block counts.
__global__ __launch_bounds__(1024) void k_colscan(const int* __restrict__ blockHist,
                                                  int* __restrict__ offsL,
                                                  int* __restrict__ colTot) {
  __shared__ int sh[1024];
  int c = blockIdx.x, t = threadIdx.x;
  int v = (t < EB) ? blockHist[t * NB + c] : 0;
  sh[t] = v;
  __syncthreads();
  for (int off = 1; off < 1024; off <<= 1) {
    int u = (t >= off) ? sh[t - off] : 0;
    __syncthreads();
    sh[t] += u;
    __syncthreads();
  }
  if (t < EB) offsL[t * NB + c] = sh[t] - v;  // exclusive within column
  if (t == EB - 1) colTot[c] = sh[t];
}

// Pass 3: exclusive scan of the 256 bucket totals -> bucket bases.
__global__ __launch_bounds__(256) void k_basescan(const int* __restrict__ colTot,
                                                  int* __restrict__ base) {
  __shared__ int sh[256];
  int t = threadIdx.x;
  int v = colTot[t];
  sh[t] = v;
  __syncthreads();
  for (int off = 1; off < 256; off <<= 1) {
    int u = (t >= off) ? sh[t - off] : 0;
    __syncthreads();
    sh[t] += u;
    __syncthreads();
  }
  base[t] = sh[t] - v;
  if (t == 255) base[256] = sh[255];
}

// Pass 4: scatter (src,dst) into bucket-partitioned array; rank via LDS atomic.
__global__ __launch_bounds__(256) void k_escat(const int* __restrict__ src,
                                               const int* __restrict__ dst,
                                               const int* __restrict__ offsL,
                                               const int* __restrict__ base,
                                               int2* __restrict__ ed) {
  __shared__ int h[NB];
  h[threadIdx.x] = 0;
  __syncthreads();
  int eb = blockIdx.x * 2048;
  const int* ofs = offsL + blockIdx.x * NB;
#pragma unroll
  for (int i = 0; i < 8; i++) {
    int e = eb + i * 256 + threadIdx.x;
    if (e < NE) {
      int d = dst[e];
      int c = d / BSZ;
      int r = atomicAdd(&h[c], 1);
      ed[base[c] + ofs[c] + r] = make_int2(src[e], d);
    }
  }
}

// Pass 5: one block per bucket; LDS cursors assign ELL slots; emit deg[].
__global__ __launch_bounds__(256) void k_ellfill(const int2* __restrict__ ed,
                                                 const int* __restrict__ base,
                                                 int* __restrict__ ell,
                                                 int* __restrict__ deg) {
  __shared__ int cur[BSZ];
  int c = blockIdx.x;
  for (int i = threadIdx.x; i < BSZ; i += 256) cur[i] = 0;
  __syncthreads();
  int lo = base[c], hi = base[c + 1];
  int n0 = c * BSZ;
  for (int e = lo + threadIdx.x; e < hi; e += 256) {
    int2 sd = ed[e];
    int slot = atomicAdd(&cur[sd.y - n0], 1);
    if (slot < 64) ell[sd.y * 64 + slot] = sd.x;
  }
  __syncthreads();
  for (int i = threadIdx.x; i < BSZ; i += 256) {
    int n = n0 + i;
    if (n < NN) deg[n] = min(cur[i], 64);
  }
}

// ---------------------------------------------------------------------------
// agg[n] = (1+eps) * pre(x[n]) + sum_{s in N(n)} pre(x[s]); output bf16.
// MODE 0: f32 input, pre=identity. MODE 1: bf16 input, pre=BN1 affine.
// 32 lanes per node (2 feats/lane) -> 8 rows in flight per wave; 4-wide
// unrolled neighbor loop with independent accumulator pairs.
template <int MODE>
__global__ __launch_bounds__(256) void k_gather(const float* __restrict__ xf,
                                                const unsigned short* __restrict__ xb,
                                                const int* __restrict__ deg,
                                                const int* __restrict__ ell,
                                                const float* __restrict__ eps,
                                                const float* __restrict__ AB,
                                                unsigned short* __restrict__ agg) {
  const int lane = threadIdx.x & 31;           // feature pair id
  const int slot = threadIdx.x >> 5;           // node slot in block (0..7)
  const int n = blockIdx.x * 8 + slot;         // 12500 blocks * 8 = NN exact
  const int fo = 2 * lane;
  float A0 = 1.0f, B0 = 0.0f, A1 = 1.0f, B1 = 0.0f;
  if (MODE) { A0 = AB[fo]; B0 = AB[64 + fo]; A1 = AB[fo + 1]; B1 = AB[64 + fo + 1]; }
  float s0, s1;
  if (MODE) {
    ushort2 u = *(const ushort2*)(xb + n * 64 + fo);
    s0 = fmaf(bf2f(u.x), A0, B0);
    s1 = fmaf(bf2f(u.y), A1, B1);
  } else {
    float2 u = *(const float2*)(xf + n * 64 + fo);
    s0 = u.x;
    s1 = u.y;
  }
  const float es = 1.0f + eps[0];
  float a0 = es * s0, a1 = es * s1;
  float b0 = 0, b1 = 0, c0 = 0, c1 = 0, d0 = 0, d1 = 0;
  const int cnt = deg[n];
  const int* row = ell + n * 64;
  const int4* r4 = (const int4*)row;
  int j = 0;
  for (; j + 4 <= cnt; j += 4) {
    int4 s4 = r4[j >> 2];
    if (MODE) {
      ushort2 u0 = *(const ushort2*)(xb + s4.x * 64 + fo);
      ushort2 u1 = *(const ushort2*)(xb + s4.y * 64 + fo);
      ushort2 u2 = *(const ushort2*)(xb + s4.z * 64 + fo);
      ushort2 u3 = *(const ushort2*)(xb + s4.w * 64 + fo);
      a0 = fmaf(bf2f(u0.x), A0, a0); a1 = fmaf(bf2f(u0.y), A1, a1);
      b0 = fmaf(bf2f(u1.x), A0, b0); b1 = fmaf(bf2f(u1.y), A1, b1);
      c0 = fmaf(bf2f(u2.x), A0, c0); c1 = fmaf(bf2f(u2.y), A1, c1);
      d0 = fmaf(bf2f(u3.x), A0, d0); d1 = fmaf(bf2f(u3.y), A1, d1);
      a0 += B0; a1 += B1; b0 += B0; b1 += B1;  // add shift per neighbor
      c0 += B0; c1 += B1; d0 += B0; d1 += B1;
    } else {
      float2 u0 = *(const float2*)(xf + s4.x * 64 + fo);
      float2 u1 = *(const float2*)(xf + s4.y * 64 + fo);
      float2 u2 = *(const float2*)(xf + s4.z * 64 + fo);
      float2 u3 = *(const float2*)(xf + s4.w * 64 + fo);
      a0 += u0.x; a1 += u0.y;
      b0 += u1.x; b1 += u1.y;
      c0 += u2.x; c1 += u2.y;
      d0 += u3.x; d1 += u3.y;
    }
  }
  for (; j < cnt; j++) {
    int s = row[j];
    if (MODE) {
      ushort2 u = *(const ushort2*)(xb + s * 64 + fo);
      a0 += fmaf(bf2f(u.x), A0, B0);
      a1 += fmaf(bf2f(u.y), A1, B1);
    } else {
      float2 u = *(const float2*)(xf + s * 64 + fo);
      a0 += u.x;
      a1 += u.y;
    }
  }
  float r0 = (a0 + b0) + (c0 + d0);
  float r1 = (a1 + b1) + (c1 + d1);
  ushort2 st;
  st.x = f2bf(r0);
  st.y = f2bf(r1);
  *(ushort2*)(agg + n * 64 + fo) = st;
}

// ---------------------------------------------------------------------------
// h2 = relu(relu(agg@Wa+ba)@Wb+bb) via bf16 MFMA 16x16x32; BN stats to f64.
__global__ __launch_bounds__(256) void k_mlp_mfma(
    const unsigned short* __restrict__ agg, const unsigned short* __restrict__ Wab,
    const float* __restrict__ ba, const float* __restrict__ bb,
    unsigned short* __restrict__ h2, double* __restrict__ stats) {
  const int l = threadIdx.x & 63;
  const int wv = threadIdx.x >> 6;
  const int l16 = l & 15, quad = l >> 4;

  short8 wfa[4][2], wfb[4][2];
#pragma unroll
  for (int c = 0; c < 4; c++)
#pragma unroll
    for (int t = 0; t < 2; t++)
#pragma unroll
      for (int j = 0; j < 8; j++) {
        int k = t * 32 + quad * 8 + j, nn = c * 16 + l16;
        wfa[c][t][j] = (short)Wab[k * 64 + nn];
        wfb[c][t][j] = (short)Wab[4096 + k * 64 + nn];
      }
  float bia[4], bib[4];
#pragma unroll
  for (int c = 0; c < 4; c++) { bia[c] = ba[c * 16 + l16]; bib[c] = bb[c * 16 + l16]; }

  __shared__ float Hs[4][16][68];
  __shared__ float sS[4][64], sQ[4][64];
  float ssum[4] = {0, 0, 0, 0}, ssq[4] = {0, 0, 0, 0};

  const int totw = gridDim.x * 4;
  for (int tile = blockIdx.x * 4 + wv; tile < NN / 16; tile += totw) {
    const int r0 = tile * 16;
    const unsigned short* ap = agg + (r0 + l16) * 64 + quad * 8;
    short8 a0 = *(const short8*)ap;
    short8 a1 = *(const short8*)(ap + 32);
#pragma unroll
    for (int c = 0; c < 4; c++) {
      floatx4 acc = {0.f, 0.f, 0.f, 0.f};
      acc = __builtin_amdgcn_mfma_f32_16x16x32_bf16(a0, wfa[c][0], acc, 0, 0, 0);
      acc = __builtin_amdgcn_mfma_f32_16x16x32_bf16(a1, wfa[c][1], acc, 0, 0, 0);
#pragma unroll
      for (int r = 0; r < 4; r++)
        Hs[wv][quad * 4 + r][c * 16 + l16] = fmaxf(acc[r] + bia[c], 0.0f);
    }
    short8 a20, a21;
#pragma unroll
    for (int j = 0; j < 8; j++) {
      a20[j] = (short)f2bf(Hs[wv][l16][quad * 8 + j]);
      a21[j] = (short)f2bf(Hs[wv][l16][32 + quad * 8 + j]);
    }
#pragma unroll
    for (int c = 0; c < 4; c++) {
      floatx4 acc = {0.f, 0.f, 0.f, 0.f};
      acc = __builtin_amdgcn_mfma_f32_16x16x32_bf16(a20, wfb[c][0], acc, 0, 0, 0);
      acc = __builtin_amdgcn_mfma_f32_16x16x32_bf16(a21, wfb[c][1], acc, 0, 0, 0);
#pragma unroll
      for (int r = 0; r < 4; r++) {
        float v = fmaxf(acc[r] + bib[c], 0.0f);
        h2[(r0 + quad * 4 + r) * 64 + c * 16 + l16] = f2bf(v);
        ssum[c] += v;
        ssq[c] += v * v;
      }
    }
  }
#pragma unroll
  for (int c = 0; c < 4; c++) {
    float s = ssum[c], q = ssq[c];
    s += __shfl_xor(s, 16, 64); s += __shfl_xor(s, 32, 64);
    q += __shfl_xor(q, 16, 64); q += __shfl_xor(q, 32, 64);
    if (quad == 0) { sS[wv][c * 16 + l16] = s; sQ[wv][c * 16 + l16] = q; }
  }
  __syncthreads();
  if (threadIdx.x < 64) {
    int ff = threadIdx.x;
    float s = sS[0][ff] + sS[1][ff] + sS[2][ff] + sS[3][ff];
    float q = sQ[0][ff] + sQ[1][ff] + sQ[2][ff] + sQ[3][ff];
    unsafeAtomicAdd(&stats[ff], (double)s);
    unsafeAtomicAdd(&stats[64 + ff], (double)q);
  }
}

// ---------------------------------------------------------------------------
// stats -> per-feature affine A (scale), B (shift): out = h*A + B
__global__ void k_bnfin(const double* __restrict__ stats, const float* __restrict__ gam,
                        const float* __restrict__ bet, float* __restrict__ AB) {
  int f = threadIdx.x;  // 64 threads
  double mean = stats[f] * (1.0 / NN);
  double var = stats[64 + f] * (1.0 / NN) - mean * mean;
  if (var < 0.0) var = 0.0;
  float rstd = (float)(1.0 / sqrt(var + 1e-5));
  float A = gam[f] * rstd;
  float B = bet[f] - (float)mean * A;
  AB[f] = A;
  AB[64 + f] = B;
}

// ---------------------------------------------------------------------------
// h = BN2(h2); out[0:N*64] = h; out[N*64:] = log_softmax(h) per row.
__global__ __launch_bounds__(256) void k_out(const unsigned short* __restrict__ h2,
                                             const float* __restrict__ AB,
                                             float* __restrict__ out) {
  int f = threadIdx.x & 63;
  int n = blockIdx.x * 4 + (threadIdx.x >> 6);  // 25000*4 = NN exact
  float v = bf2f(h2[n * 64 + f]);
  float h = fmaf(v, AB[f], AB[64 + f]);
  float m = h;
#pragma unroll
  for (int off = 32; off; off >>= 1) m = fmaxf(m, __shfl_xor(m, off, 64));
  float e = expf(h - m);
  float ssum = e;
#pragma unroll
  for (int off = 32; off; off >>= 1) ssum += __shfl_xor(ssum, off, 64);
  float lsm = (h - m) - logf(ssum);
  out[n * 64 + f] = h;
  out[(size_t)NN * 64 + n * 64 + f] = lsm;
}

// ---------------------------------------------------------------------------
extern "C" void kernel_launch(void* const* d_in, const int* in_sizes, int n_in,
                              void* d_out, int out_size, void* d_ws, size_t ws_size,
                              hipStream_t stream) {
  const float* x = (const float*)d_in[0];
  const int* ei = (const int*)d_in[1];  // [2, E] as int32
  const float* W1 = (const float*)d_in[2];
  const float* b1 = (const float*)d_in[3];
  const float* W2 = (const float*)d_in[4];
  const float* b2 = (const float*)d_in[5];
  const float* g1 = (const float*)d_in[6];
  const float* bt1 = (const float*)d_in[7];
  const float* e1 = (const float*)d_in[8];
  const float* W3 = (const float*)d_in[9];
  const float* b3 = (const float*)d_in[10];
  const float* W4 = (const float*)d_in[11];
  const float* b4 = (const float*)d_in[12];
  const float* g2 = (const float*)d_in[13];
  const float* bt2 = (const float*)d_in[14];
  const float* e2 = (const float*)d_in[15];
  const int* src = ei;
  const int* dst = ei + NE;

  char* ws = (char*)d_ws;
  unsigned short* aggb = (unsigned short*)(ws);             // 12.8 MB bf16
  unsigned short* h2b = (unsigned short*)(ws + 12800000);   // 12.8 MB bf16
  int* ell = (int*)(ws + 25600000);                         // 25.6 MB
  int2* ed = (int2*)(ws + 51200000);                        // 12.8 MB partitioned edges
  int* blockHist = (int*)(ws + 64000000);                   // 782*256 ints = 800,768 B
  int* offsL = (int*)(ws + 64800768);                       // 782*256 ints
  int* colTot = (int*)(ws + 65601536);                      // 256 ints
  int* base = (int*)(ws + 65602560);                        // 257 ints (pad to 1040)
  int* deg = (int*)(ws + 65603600);                         // 100000 ints
  double* st1 = (double*)(ws + 66003600);                   // 128 f64
  double* st2 = (double*)(ws + 66004624);                   // 128 f64
  float* AB1 = (float*)(ws + 66005648);                     // 128 f32
  float* AB2 = (float*)(ws + 66006160);                     // 128 f32
  unsigned short* Wbb = (unsigned short*)(ws + 66006672);   // 4*4096 bf16
  float* out = (float*)d_out;

  hipMemsetAsync(ws + 66003600, 0, 2048, stream);  // zero st1+st2

  k_cvtW<<<16, 256, 0, stream>>>(W1, W2, W3, W4, Wbb);

  // --- ELL build via bucket partition (no global atomics) ---
  k_phist<<<EB, 256, 0, stream>>>(dst, blockHist);
  k_colscan<<<NB, 1024, 0, stream>>>(blockHist, offsL, colTot);
  k_basescan<<<1, 256, 0, stream>>>(colTot, base);
  k_escat<<<EB, 256, 0, stream>>>(src, dst, offsL, base, ed);
  k_ellfill<<<NB, 256, 0, stream>>>(ed, base, ell, deg);

  // --- Layer 1 ---
  k_gather<0><<<NN / 8, 256, 0, stream>>>(x, nullptr, deg, ell, e1, nullptr, aggb);
  k_mlp_mfma<<<391, 256, 0, stream>>>(aggb, Wbb, b1, b2, h2b, st1);
  k_bnfin<<<1, 64, 0, stream>>>(st1, g1, bt1, AB1);
  // --- Layer 2 (BN1-apply fused into the gather) ---
  k_gather<1><<<NN / 8, 256, 0, stream>>>(nullptr, h2b, deg, ell, e2, AB1, aggb);
  k_mlp_mfma<<<391, 256, 0, stream>>>(aggb, Wbb + 8192, b3, b4, h2b, st2);
  k_bnfin<<<1, 64, 0, stream>>>(st2, g2, bt2, AB2);
  // --- Epilogue: BN2 + log_softmax ---
  k_out<<<NN / 4, 256, 0, stream>>>(h2b, AB2, out);
}